// Round 1
// baseline (8752.827 us; speedup 1.0000x reference)
//
#include <hip/hip_runtime.h>
#include <hip/hip_bf16.h>

#define BB 64
#define PP 192
#define SS 36
#define PI_F 3.14159265358979323846f

// ---------------------------------------------------------------------------
// K0: broadcast priors (P,78) -> (B,P,78)
// ---------------------------------------------------------------------------
__global__ __launch_bounds__(256)
void k_init_priors(const float* __restrict__ priors, float* __restrict__ out) {
  int idx = blockIdx.x * 256 + threadIdx.x;
  if (idx < BB * PP * 78) out[idx] = priors[idx % (PP * 78)];
}

// ---------------------------------------------------------------------------
// K2: key/value maps. resize_nearest commutes with the 1x1 conv (per-pixel
// linear + per-channel affine/relu), so sample 250 pixels then project.
// One block per (b, pixel), 64 threads = 64 output channels.
// ---------------------------------------------------------------------------
__global__ __launch_bounds__(64)
void k_keyval(const float* __restrict__ fmap, int H, int W,
              const float* __restrict__ fkey_w, const float* __restrict__ fkey_scale,
              const float* __restrict__ fkey_shift,
              const float* __restrict__ fval_w, const float* __restrict__ fval_b,
              float* __restrict__ keyf, float* __restrict__ value) {
  int b = blockIdx.x / 250;
  int k = blockIdx.x % 250;
  int r = k / 25, c2 = k % 25;
  int iy = (r * H) / 10, ix = (c2 * W) / 25;   // matches numpy arange*H//oh
  __shared__ float f[64];
  int o = threadIdx.x;
  f[o] = fmap[((size_t)(b * 64 + o) * H + iy) * W + ix];
  __syncthreads();
  float ak = 0.f, av = 0.f;
#pragma unroll 8
  for (int c = 0; c < 64; ++c) {
    float fv = f[c];
    ak += fv * fkey_w[o * 64 + c];
    av += fv * fval_w[o * 64 + c];
  }
  float kf = ak * fkey_scale[o] + fkey_shift[o];
  keyf[(size_t)(b * 64 + o) * 250 + k] = kf > 0.f ? kf : 0.f;
  value[(size_t)(b * 64 + o) * 250 + k] = av + fval_b[o];
}

// ---------------------------------------------------------------------------
// K1: per-(b,p) fused: [re]gather roi_i -> cf_i convs -> cat conv -> fc -> LN
// One block (256 threads) per roi. Stage i<STAGE is recomputed exactly like
// the reference, using the sample-x positions saved when stage i ran.
// ---------------------------------------------------------------------------
template <int STAGE>
__global__ __launch_bounds__(256)
void k_main(const float* __restrict__ f0, const float* __restrict__ f1,
            const float* __restrict__ f2,
            const float* __restrict__ priors_cur,
            const float* __restrict__ convs_w,      // (3,48,64,9)
            const float* __restrict__ convs_scale,  // (3,48)
            const float* __restrict__ convs_shift,
            const float* __restrict__ cat_w,        // (64, 48*(STAGE+1), 9)
            const float* __restrict__ cat_scale,    // pre-offset by stage
            const float* __restrict__ cat_shift,
            const float* __restrict__ fc_w, const float* __restrict__ fc_b,
            const float* __restrict__ ln_g, const float* __restrict__ ln_b,
            float* __restrict__ pos_store,          // [3][B*P][36]
            float* __restrict__ roi_fc_out) {
  constexpr int NC = STAGE + 1;
  constexpr int Hs[3] = {64, 32, 16};
  constexpr int Ws[3] = {80, 40, 20};
  const float* fmaps[3] = {f0, f1, f2};

  int bp = blockIdx.x;
  int b = bp / PP;
  int tid = threadIdx.x;

  __shared__ float pos_x[SS];
  __shared__ float pos_y[SS];
  __shared__ float roi_p[64][44];          // +4 halo each side (zero pad)
  __shared__ float cf_p[NC][48][44];
  __shared__ float cat_s[64 * 36];
  __shared__ float fc_part[64][4];

  // zero halos once (gather/conv only write the 36-wide core)
  for (int idx = tid; idx < 64 * 8; idx += 256) {
    int c = idx >> 3, t = idx & 7;
    roi_p[c][t < 4 ? t : 36 + t] = 0.f;
  }
#pragma unroll
  for (int i = 0; i < NC; ++i)
    for (int idx = tid; idx < 48 * 8; idx += 256) {
      int c = idx >> 3, t = idx & 7;
      cf_p[i][c][t < 4 ? t : 36 + t] = 0.f;
    }

#pragma unroll
  for (int i = 0; i < NC; ++i) {
    const int H = Hs[i], W = Ws[i];
    // ---- sample positions for roi-stage i ----
    __syncthreads();
    if (tid < SS) {
      int j = tid, k = 35 - j;                         // prior_xs is reversed
      int sx = (int)(((float)k / 35.0f) * 71.0f);      // SAMPLE_X[k]
      float px;
      if (i == STAGE) {
        px = priors_cur[(size_t)bp * 78 + 6 + sx];
        pos_store[((size_t)STAGE * (BB * PP) + bp) * SS + j] = px;
      } else {
        px = pos_store[((size_t)i * (BB * PP) + bp) * SS + j];
      }
      pos_x[j] = px;
      float fy = 1.0f - (float)sx / 71.0f;             // PRIOR_FEAT_YS[j]
      pos_y[j] = fy * (float)(H - 1);
    }
    __syncthreads();

    // ---- bilinear gather: roi (64 x 36) ----
    {
      const float* fb = fmaps[i] + (size_t)b * 64 * H * W;
      for (int idx = tid; idx < 64 * 36; idx += 256) {
        int c = idx / 36, j = idx % 36;
        float x = pos_x[j] * (float)(W - 1);
        float y = pos_y[j];
        float x0 = floorf(x), y0 = floorf(y);
        float wx = x - x0, wy = y - y0;
        const float* fcp = fb + (size_t)c * H * W;
        float xs2[2] = {x0, x0 + 1.f};
        float ys2[2] = {y0, y0 + 1.f};
        float wxs[2] = {1.f - wx, wx};
        float wys[2] = {1.f - wy, wy};
        float acc = 0.f;
#pragma unroll
        for (int ty = 0; ty < 2; ++ty)
#pragma unroll
          for (int tx = 0; tx < 2; ++tx) {
            float xf = xs2[tx], yf = ys2[ty];
            bool v = (xf >= 0.f) && (xf <= (float)(W - 1)) &&
                     (yf >= 0.f) && (yf <= (float)(H - 1));
            int xi = (int)fminf(fmaxf(xf, 0.f), (float)(W - 1));
            int yi = (int)fminf(fmaxf(yf, 0.f), (float)(H - 1));
            float val = fcp[yi * W + xi];
            acc += v ? val * (wxs[tx] * wys[ty]) : 0.f;
          }
        roi_p[c][4 + j] = acc;
      }
    }
    __syncthreads();

    // ---- conv1d (48 out, 64 in, K=9, pad 4) + affine + relu -> cf_p[i] ----
    if (tid < 192) {
      int o = tid >> 2, jb = tid & 3;   // 9 consecutive j per thread
      float acc[9];
#pragma unroll
      for (int jj = 0; jj < 9; ++jj) acc[jj] = 0.f;
      const float* w = convs_w + (size_t)(i * 48 + o) * 576;
      for (int c = 0; c < 64; ++c) {
        float wr[9];
#pragma unroll
        for (int k = 0; k < 9; ++k) wr[k] = w[c * 9 + k];
        float xr[17];
#pragma unroll
        for (int t = 0; t < 17; ++t) xr[t] = roi_p[c][jb * 9 + t];
#pragma unroll
        for (int jj = 0; jj < 9; ++jj)
#pragma unroll
          for (int k = 0; k < 9; ++k) acc[jj] += xr[jj + k] * wr[k];
      }
      float sc = convs_scale[i * 48 + o], sh = convs_shift[i * 48 + o];
#pragma unroll
      for (int jj = 0; jj < 9; ++jj) {
        float v = acc[jj] * sc + sh;
        cf_p[i][o][4 + jb * 9 + jj] = v > 0.f ? v : 0.f;
      }
    }
  }
  __syncthreads();

  // ---- cat conv (64 out, 48*NC in, K=9) + affine + relu ----
  {
    int o = tid >> 2, jb = tid & 3;
    float acc[9];
#pragma unroll
    for (int jj = 0; jj < 9; ++jj) acc[jj] = 0.f;
    const float* w = cat_w + (size_t)o * (NC * 48 * 9);
#pragma unroll
    for (int i = 0; i < NC; ++i)
      for (int c = 0; c < 48; ++c) {
        float wr[9];
#pragma unroll
        for (int k = 0; k < 9; ++k) wr[k] = w[(i * 48 + c) * 9 + k];
        float xr[17];
#pragma unroll
        for (int t = 0; t < 17; ++t) xr[t] = cf_p[i][c][jb * 9 + t];
#pragma unroll
        for (int jj = 0; jj < 9; ++jj)
#pragma unroll
          for (int k = 0; k < 9; ++k) acc[jj] += xr[jj + k] * wr[k];
      }
    float sc = cat_scale[o], sh = cat_shift[o];
#pragma unroll
    for (int jj = 0; jj < 9; ++jj) {
      float v = acc[jj] * sc + sh;
      cat_s[o * 36 + jb * 9 + jj] = v > 0.f ? v : 0.f;
    }
  }
  __syncthreads();

  // ---- fc: (2304) @ fc_w.T -> 64, split K into 4 chunks per h ----
  {
    int h = tid & 63, q = tid >> 6;     // q uniform per wave
    const float* w = fc_w + (size_t)h * 2304 + q * 576;
    const float* xs = cat_s + q * 576;
    float acc = 0.f;
    for (int t = 0; t < 576; ++t) acc += xs[t] * w[t];
    fc_part[h][q] = acc;
  }
  __syncthreads();

  // ---- layernorm + relu (wave 0 holds all 64 h) ----
  if (tid < 64) {
    int h = tid;
    float y = fc_part[h][0] + fc_part[h][1] + fc_part[h][2] + fc_part[h][3] + fc_b[h];
    float s = y;
#pragma unroll
    for (int off = 32; off > 0; off >>= 1) s += __shfl_xor(s, off, 64);
    float mu = s * (1.f / 64.f);
    float d = y - mu;
    float v2 = d * d;
#pragma unroll
    for (int off = 32; off > 0; off >>= 1) v2 += __shfl_xor(v2, off, 64);
    float var = v2 * (1.f / 64.f);
    float r = d / sqrtf(var + 1e-5f) * ln_g[h] + ln_b[h];
    roi_fc_out[(size_t)bp * 64 + h] = r > 0.f ? r : 0.f;
  }
}

// ---------------------------------------------------------------------------
// K3: attention (250 keys) + MLP heads + tan epilogue + cascade update.
// One block (256 threads) per (b,p).
// ---------------------------------------------------------------------------
__global__ __launch_bounds__(256)
void k_att(const float* __restrict__ roi_fc,
           const float* __restrict__ keyf, const float* __restrict__ value,
           const float* __restrict__ fq_w, const float* __restrict__ fq_b,
           const float* __restrict__ attW_w, const float* __restrict__ attW_b,
           const float* __restrict__ cls_mlp_w, const float* __restrict__ cls_mlp_b,
           const float* __restrict__ reg_mlp_w, const float* __restrict__ reg_mlp_b,
           const float* __restrict__ cls_head_w, const float* __restrict__ cls_head_b,
           const float* __restrict__ reg_head_w, const float* __restrict__ reg_head_b,
           const float* __restrict__ priors_cur,
           float* __restrict__ priors_next,   // null on final stage
           float* __restrict__ preds) {
  int bp = blockIdx.x;
  int b = bp / PP, p = bp % PP;
  int tid = threadIdx.x;
  __shared__ float rf_s[64], q_s[64], x_s[64], h1c[64], h1r[64], h2c[64], h2r[64];
  __shared__ float sim[256], red[256];
  __shared__ float cls_s[2], reg_s[76];

  if (tid < 64) {
    float rf = roi_fc[(size_t)bp * 64 + tid];
    rf_s[tid] = rf;
    float q = rf * fq_w[p] + fq_b[p];
    q_s[tid] = q > 0.f ? q : 0.f;
  }
  __syncthreads();

  float sc = -1e30f;
  if (tid < 250) {
    const float* kcol = keyf + (size_t)b * 64 * 250 + tid;
    float acc = 0.f;
#pragma unroll 8
    for (int c = 0; c < 64; ++c) acc += q_s[c] * kcol[c * 250];
    sc = acc * 0.125f;   // C^-0.5
  }
  red[tid] = sc;
  __syncthreads();
  for (int off = 128; off > 0; off >>= 1) {
    if (tid < off) red[tid] = fmaxf(red[tid], red[tid + off]);
    __syncthreads();
  }
  float m = red[0];
  __syncthreads();
  float e = (tid < 250) ? expf(sc - m) : 0.f;
  red[tid] = e;
  __syncthreads();
  for (int off = 128; off > 0; off >>= 1) {
    if (tid < off) red[tid] += red[tid + off];
    __syncthreads();
  }
  float ssum = red[0];
  sim[tid] = e / ssum;
  __syncthreads();

  if (tid < 64) {
    const float* vrow = value + ((size_t)b * 64 + tid) * 250;
    float acc = 0.f;
    for (int k = 0; k < 250; ++k) acc += sim[k] * vrow[k];
    float ctx = acc * attW_w[p] + attW_b[p];
    x_s[tid] = rf_s[tid] + ctx;
  }
  __syncthreads();

  if (tid < 64) {
    int o = tid;
    float ac = cls_mlp_b[o], ar = reg_mlp_b[o];
    const float* wc = cls_mlp_w + o * 64;
    const float* wr = reg_mlp_w + o * 64;
    for (int c = 0; c < 64; ++c) { float xv = x_s[c]; ac += xv * wc[c]; ar += xv * wr[c]; }
    h1c[o] = ac > 0.f ? ac : 0.f;
    h1r[o] = ar > 0.f ? ar : 0.f;
  }
  __syncthreads();
  if (tid < 64) {
    int o = tid;
    float ac = cls_mlp_b[64 + o], ar = reg_mlp_b[64 + o];
    const float* wc = cls_mlp_w + 4096 + o * 64;
    const float* wr = reg_mlp_w + 4096 + o * 64;
    for (int c = 0; c < 64; ++c) { ac += h1c[c] * wc[c]; ar += h1r[c] * wr[c]; }
    h2c[o] = ac > 0.f ? ac : 0.f;
    h2r[o] = ar > 0.f ? ar : 0.f;
  }
  __syncthreads();
  if (tid < 2) {
    float a = cls_head_b[tid];
    const float* w = cls_head_w + tid * 64;
    for (int c = 0; c < 64; ++c) a += h2c[c] * w[c];
    cls_s[tid] = a;
  }
  if (tid >= 64 && tid < 64 + 76) {
    int o = tid - 64;
    float a = reg_head_b[o];
    const float* w = reg_head_w + o * 64;
    for (int c = 0; c < 64; ++c) a += h2r[c] * w[c];
    reg_s[o] = a;
  }
  __syncthreads();

  const float* pc = priors_cur + (size_t)bp * 78;
  float* po = preds + (size_t)bp * 78;
  float p0 = pc[2] + reg_s[0];
  float p1 = pc[3] + reg_s[1];
  float p2 = pc[4] + reg_s[2];
  if (tid == 0) {
    po[0] = cls_s[0]; po[1] = cls_s[1];
    po[2] = p0; po[3] = p1; po[4] = p2;
    po[5] = reg_s[3];
    if (priors_next) {
      float* pn = priors_next + (size_t)bp * 78;
      pn[0] = cls_s[0]; pn[1] = cls_s[1];
      pn[2] = p0; pn[3] = p1; pn[4] = p2; pn[5] = reg_s[3];
    }
  }
  if (tid < 72) {
    float py = 1.0f - (float)tid / 71.0f;           // PRIOR_YS[i]
    float t = tanf(p2 * PI_F + 1e-5f);
    float offs = (p1 * 639.0f + (1.0f - py - p0) * 512.0f / t) / 639.0f;
    po[6 + tid] = offs + reg_s[4 + tid];
    if (priors_next) priors_next[(size_t)bp * 78 + 6 + tid] = offs;
  }
}

// ---------------------------------------------------------------------------
extern "C" void kernel_launch(void* const* d_in, const int* in_sizes, int n_in,
                              void* d_out, int out_size, void* d_ws, size_t ws_size,
                              hipStream_t stream) {
  (void)in_sizes; (void)n_in; (void)out_size; (void)ws_size;
  const float* feat[3] = {(const float*)d_in[0], (const float*)d_in[1], (const float*)d_in[2]};
  const float* priors      = (const float*)d_in[3];
  const float* convs_w     = (const float*)d_in[4];
  const float* convs_scale = (const float*)d_in[5];
  const float* convs_shift = (const float*)d_in[6];
  const float* cat_w[3]    = {(const float*)d_in[7], (const float*)d_in[8], (const float*)d_in[9]};
  const float* cat_scale   = (const float*)d_in[10];
  const float* cat_shift   = (const float*)d_in[11];
  const float* fkey_w      = (const float*)d_in[12];
  const float* fkey_scale  = (const float*)d_in[13];
  const float* fkey_shift  = (const float*)d_in[14];
  const float* fval_w      = (const float*)d_in[15];
  const float* fval_b      = (const float*)d_in[16];
  const float* fq_w        = (const float*)d_in[17];
  const float* fq_b        = (const float*)d_in[18];
  const float* attW_w      = (const float*)d_in[19];
  const float* attW_b      = (const float*)d_in[20];
  const float* fc_w        = (const float*)d_in[21];
  const float* fc_b        = (const float*)d_in[22];
  const float* ln_g        = (const float*)d_in[23];
  const float* ln_b        = (const float*)d_in[24];
  const float* cls_mlp_w   = (const float*)d_in[25];
  const float* cls_mlp_b   = (const float*)d_in[26];
  const float* reg_mlp_w   = (const float*)d_in[27];
  const float* reg_mlp_b   = (const float*)d_in[28];
  const float* cls_head_w  = (const float*)d_in[29];
  const float* cls_head_b  = (const float*)d_in[30];
  const float* reg_head_w  = (const float*)d_in[31];
  const float* reg_head_b  = (const float*)d_in[32];
  float* out = (float*)d_out;

  // workspace layout (floats), ~24.3 MB total
  float* wsf = (float*)d_ws;
  float* priA    = wsf;                        // B*P*78
  float* priB    = priA + (size_t)BB * PP * 78;
  float* roi_fc  = priB + (size_t)BB * PP * 78;   // B*P*64
  float* keyb    = roi_fc + (size_t)BB * PP * 64; // B*64*250
  float* valb    = keyb + (size_t)BB * 64 * 250;
  float* pos_st  = valb + (size_t)BB * 64 * 250;  // 3*B*P*36

  const int HW[3][2] = {{64, 80}, {32, 40}, {16, 20}};

  k_init_priors<<<dim3((BB * PP * 78 + 255) / 256), dim3(256), 0, stream>>>(priors, priA);

  float* pcur = priA;
  float* pnext = priB;
  for (int s = 0; s < 3; ++s) {
    int H = HW[s][0], W = HW[s][1];
    k_keyval<<<dim3(BB * 250), dim3(64), 0, stream>>>(
        feat[s], H, W, fkey_w, fkey_scale, fkey_shift, fval_w, fval_b, keyb, valb);

    if (s == 0) {
      k_main<0><<<dim3(BB * PP), dim3(256), 0, stream>>>(
          feat[0], feat[1], feat[2], pcur, convs_w, convs_scale, convs_shift,
          cat_w[0], cat_scale + 0, cat_shift + 0, fc_w, fc_b, ln_g, ln_b,
          pos_st, roi_fc);
    } else if (s == 1) {
      k_main<1><<<dim3(BB * PP), dim3(256), 0, stream>>>(
          feat[0], feat[1], feat[2], pcur, convs_w, convs_scale, convs_shift,
          cat_w[1], cat_scale + 64, cat_shift + 64, fc_w, fc_b, ln_g, ln_b,
          pos_st, roi_fc);
    } else {
      k_main<2><<<dim3(BB * PP), dim3(256), 0, stream>>>(
          feat[0], feat[1], feat[2], pcur, convs_w, convs_scale, convs_shift,
          cat_w[2], cat_scale + 128, cat_shift + 128, fc_w, fc_b, ln_g, ln_b,
          pos_st, roi_fc);
    }

    k_att<<<dim3(BB * PP), dim3(256), 0, stream>>>(
        roi_fc, keyb, valb, fq_w, fq_b, attW_w, attW_b,
        cls_mlp_w, cls_mlp_b, reg_mlp_w, reg_mlp_b,
        cls_head_w, cls_head_b, reg_head_w, reg_head_b,
        pcur, (s < 2) ? pnext : (float*)nullptr,
        out + (size_t)s * BB * PP * 78);

    float* tmp = pcur; pcur = pnext; pnext = tmp;
  }
}

// Round 2
// 3047.602 us; speedup vs baseline: 2.8720x; 2.8720x over previous
//
#include <hip/hip_runtime.h>
#include <hip/hip_bf16.h>

#define BB 64
#define PP 192
#define SS 36
#define PI_F 3.14159265358979323846f

typedef __attribute__((ext_vector_type(8))) __bf16 bf16x8;
typedef __attribute__((ext_vector_type(4))) float f32x4;
typedef __attribute__((ext_vector_type(8))) unsigned short us8;

__device__ inline unsigned short f2bf(float f) {
  unsigned int u = __builtin_bit_cast(unsigned int, f);
  unsigned int r = (u + 0x7FFFu + ((u >> 16) & 1u)) >> 16;
  return (unsigned short)r;
}

__device__ inline bf16x8 ld8(const unsigned short* p) {
  us8 v = *(const us8*)p;
  return __builtin_bit_cast(bf16x8, v);
}

// ---------------------------------------------------------------------------
// K0: broadcast priors (P,78) -> (B,P,78)
// ---------------------------------------------------------------------------
__global__ __launch_bounds__(256)
void k_init_priors(const float* __restrict__ priors, float* __restrict__ out) {
  int idx = blockIdx.x * 256 + threadIdx.x;
  if (idx < BB * PP * 78) out[idx] = priors[idx % (PP * 78)];
}

// ---------------------------------------------------------------------------
// Repack weights to bf16 MFMA-A layouts (runs every launch; cheap).
// Wr[s][k][o48][c64]; Wc stage regions [i][k][o64][c64 (48 real + 16 zero)];
// fw[h][kp] with kp = j*64 + c  (fc K-order permuted to j-major)
// ---------------------------------------------------------------------------
__global__ __launch_bounds__(256)
void k_repack(const float* __restrict__ cw,
              const float* __restrict__ c0, const float* __restrict__ c1,
              const float* __restrict__ c2, const float* __restrict__ fcw,
              unsigned short* __restrict__ Wr, unsigned short* __restrict__ Wc,
              unsigned short* __restrict__ fw) {
  int idx = blockIdx.x * 256 + threadIdx.x;
  if (idx < 82944) {
    int c = idx & 63; int t = idx >> 6; int o = t % 48; t /= 48;
    int k = t % 9; int s = t / 9;
    Wr[idx] = f2bf(cw[((size_t)(s * 48 + o) * 64 + c) * 9 + k]);
  } else if (idx < 82944 + 221184) {
    int r = idx - 82944;
    int s, base, NC;
    if (r < 36864)            { s = 0; base = 0;      NC = 1; }
    else if (r < 110592)      { s = 1; base = 36864;  NC = 2; }
    else                      { s = 2; base = 110592; NC = 3; }
    int q = r - base;
    int c = q & 63; int t = q >> 6; int o = t & 63; t >>= 6;
    int k = t % 9; int i = t / 9;
    const float* src = (s == 0) ? c0 : (s == 1) ? c1 : c2;
    float v = (c < 48) ? src[((size_t)o * (NC * 48) + i * 48 + c) * 9 + k] : 0.f;
    Wc[r] = f2bf(v);
  } else if (idx < 82944 + 221184 + 147456) {
    int q = idx - (82944 + 221184);
    int h = q / 2304; int kp = q % 2304; int j = kp >> 6; int c = kp & 63;
    fw[q] = f2bf(fcw[(size_t)h * 2304 + c * 36 + j]);
  }
}

// ---------------------------------------------------------------------------
// K2: key/value maps (unchanged from round 1).
// ---------------------------------------------------------------------------
__global__ __launch_bounds__(64)
void k_keyval(const float* __restrict__ fmap, int H, int W,
              const float* __restrict__ fkey_w, const float* __restrict__ fkey_scale,
              const float* __restrict__ fkey_shift,
              const float* __restrict__ fval_w, const float* __restrict__ fval_b,
              float* __restrict__ keyf, float* __restrict__ value) {
  int b = blockIdx.x / 250;
  int k = blockIdx.x % 250;
  int r = k / 25, c2 = k % 25;
  int iy = (r * H) / 10, ix = (c2 * W) / 25;
  __shared__ float f[64];
  int o = threadIdx.x;
  f[o] = fmap[((size_t)(b * 64 + o) * H + iy) * W + ix];
  __syncthreads();
  float ak = 0.f, av = 0.f;
#pragma unroll 8
  for (int c = 0; c < 64; ++c) {
    float fv = f[c];
    ak += fv * fkey_w[o * 64 + c];
    av += fv * fval_w[o * 64 + c];
  }
  float kf = ak * fkey_scale[o] + fkey_shift[o];
  keyf[(size_t)(b * 64 + o) * 250 + k] = kf > 0.f ? kf : 0.f;
  value[(size_t)(b * 64 + o) * 250 + k] = av + fval_b[o];
}

// ---------------------------------------------------------------------------
// K1a: fused gather + conv_s (MFMA). Block = 8 rois. Packed position axis
// p = roi_local*44 + r, r = j+4 (4-wide zero halos). Output tiles n=16 over
// p in [0,352); halo outputs predicated off; cross-roi B reads land in the
// neighbor's zero-halo rows, so the 9-shift GEMM is exact.
// ---------------------------------------------------------------------------
template <int STAGE>
__global__ __launch_bounds__(256)
void k_gatherconv(const float* __restrict__ fmap,
                  const float* __restrict__ priors_cur,
                  const unsigned short* __restrict__ Wr,   // [9][48][64] this stage
                  const float* __restrict__ cscale, const float* __restrict__ cshift,
                  unsigned short* __restrict__ cfg) {      // [12288][36][48]
  constexpr int H = (STAGE == 0) ? 64 : (STAGE == 1) ? 32 : 16;
  constexpr int W = (STAGE == 0) ? 80 : (STAGE == 1) ? 40 : 20;

  __shared__ float posx[8][36], posy[8][36];
  __shared__ __align__(16) unsigned short Xs[360][64];   // 4 front slack + 352 + 4 back

  int tid = threadIdx.x;
  int r0 = blockIdx.x * 8;

  for (int idx = tid; idx < 288; idx += 256) {
    int q = idx / 36, j = idx % 36;
    int bp = r0 + q;
    int k = 35 - j;
    int sx = (int)(((float)k / 35.0f) * 71.0f);
    float px = priors_cur[(size_t)bp * 78 + 6 + sx];
    posx[q][j] = px * (float)(W - 1);
    float fy = 1.0f - (float)sx / 71.0f;
    posy[q][j] = fy * (float)(H - 1);
  }
  __syncthreads();

  // gather (fp32 -> bf16) with XOR-swizzled chunk placement
  for (int idx = tid; idx < 360 * 64; idx += 256) {
    int row = idx >> 6, c = idx & 63;
    int p = row - 4;
    float val = 0.f;
    if (p >= 0 && p < 352) {
      int q = p / 44, x = p % 44;
      if (x >= 4 && x < 40) {
        int j = x - 4;
        int b = (r0 + q) / PP;
        float fx = posx[q][j];
        float fy = posy[q][j];
        float x0 = floorf(fx), y0 = floorf(fy);
        float wx = fx - x0, wy = fy - y0;
        const float* fcp = fmap + ((size_t)b * 64 + c) * H * W;
        float xs2[2] = {x0, x0 + 1.f};
        float ys2[2] = {y0, y0 + 1.f};
        float wxs[2] = {1.f - wx, wx};
        float wys[2] = {1.f - wy, wy};
#pragma unroll
        for (int ty = 0; ty < 2; ++ty)
#pragma unroll
          for (int tx = 0; tx < 2; ++tx) {
            float xf = xs2[tx], yf = ys2[ty];
            bool v = (xf >= 0.f) && (xf <= (float)(W - 1)) &&
                     (yf >= 0.f) && (yf <= (float)(H - 1));
            int xi = (int)fminf(fmaxf(xf, 0.f), (float)(W - 1));
            int yi = (int)fminf(fmaxf(yf, 0.f), (float)(H - 1));
            float s = fcp[yi * W + xi];
            val += v ? s * (wxs[tx] * wys[ty]) : 0.f;
          }
      }
    }
    int chunk = (c >> 3) ^ (row & 7);
    Xs[row][chunk * 8 + (c & 7)] = f2bf(val);
  }
  __syncthreads();

  int wv = tid >> 6, lane = tid & 63, l15 = lane & 15, quad = lane >> 4;
  f32x4 acc[3][6];
#pragma unroll
  for (int m = 0; m < 3; ++m)
#pragma unroll
    for (int s = 0; s < 6; ++s) acc[m][s] = (f32x4)0.f;

  for (int k = 0; k < 9; ++k) {
#pragma unroll
    for (int kk = 0; kk < 2; ++kk) {
      bf16x8 af[3];
#pragma unroll
      for (int m = 0; m < 3; ++m)
        af[m] = ld8(Wr + ((size_t)(k * 48 + m * 16 + l15)) * 64 + kk * 32 + quad * 8);
#pragma unroll
      for (int s = 0; s < 6; ++s) {
        int nt = wv + 4 * s;
        if (nt < 22) {
          int row = nt * 16 + l15 + k;             // = p + k
          int pc = (kk * 4 + quad) ^ (row & 7);
          bf16x8 bfr = ld8(&Xs[row][pc * 8]);
#pragma unroll
          for (int m = 0; m < 3; ++m)
            acc[m][s] = __builtin_amdgcn_mfma_f32_16x16x32_bf16(af[m], bfr, acc[m][s], 0, 0, 0);
        }
      }
    }
  }

#pragma unroll
  for (int s = 0; s < 6; ++s) {
    int nt = wv + 4 * s;
    if (nt < 22) {
      int p = nt * 16 + l15;
      int q = p / 44, x = p % 44;
      if (x >= 4 && x < 40) {
        int bp = r0 + q;
#pragma unroll
        for (int m = 0; m < 3; ++m) {
          int o0 = m * 16 + quad * 4;
          unsigned short pk[4];
#pragma unroll
          for (int rg = 0; rg < 4; ++rg) {
            float v = acc[m][s][rg] * cscale[o0 + rg] + cshift[o0 + rg];
            pk[rg] = f2bf(v > 0.f ? v : 0.f);
          }
          *(uint2*)(cfg + ((size_t)bp * 36 + (x - 4)) * 48 + o0) = *(uint2*)pk;
        }
      }
    }
  }
}

// ---------------------------------------------------------------------------
// K1b: cat conv (MFMA), accumulating over stage groups i=0..STAGE with cf_g[i]
// staged global->LDS per group. Same packed-position GEMM structure.
// ---------------------------------------------------------------------------
template <int STAGE>
__global__ __launch_bounds__(256)
void k_cat(const unsigned short* __restrict__ cfg_all,  // cf_g base, stride 12288*36*48
           const unsigned short* __restrict__ Wc,       // [NC][9][64][64] this stage
           const float* __restrict__ kscale, const float* __restrict__ kshift,
           unsigned short* __restrict__ catf) {         // [12288][36][64]
  constexpr int NC = STAGE + 1;
  __shared__ __align__(16) unsigned short cfs[360][64];
  int tid = threadIdx.x;
  int r0 = blockIdx.x * 8;
  int wv = tid >> 6, lane = tid & 63, l15 = lane & 15, quad = lane >> 4;

  f32x4 acc[4][6];
#pragma unroll
  for (int m = 0; m < 4; ++m)
#pragma unroll
    for (int s = 0; s < 6; ++s) acc[m][s] = (f32x4)0.f;

#pragma unroll
  for (int i = 0; i < NC; ++i) {
    __syncthreads();
    for (int idx = tid; idx < 360 * 8; idx += 256) {
      int row = idx >> 3, ch = idx & 7;
      int p = row - 4;
      us8 v = (us8)(unsigned short)0;
      if (p >= 0 && p < 352 && ch < 6) {
        int q = p / 44, x = p % 44;
        if (x >= 4 && x < 40) {
          const unsigned short* src = cfg_all + (size_t)i * (12288ull * 36 * 48) +
                                      ((size_t)(r0 + q) * 36 + (x - 4)) * 48 + ch * 8;
          v = *(const us8*)src;
        }
      }
      int pc = ch ^ (row & 7);
      *(us8*)&cfs[row][pc * 8] = v;
    }
    __syncthreads();

    for (int k = 0; k < 9; ++k) {
#pragma unroll
      for (int kk = 0; kk < 2; ++kk) {
        bf16x8 af[4];
#pragma unroll
        for (int m = 0; m < 4; ++m)
          af[m] = ld8(Wc + (((size_t)i * 9 + k) * 64 + m * 16 + l15) * 64 + kk * 32 + quad * 8);
#pragma unroll
        for (int s = 0; s < 6; ++s) {
          int nt = wv + 4 * s;
          if (nt < 22) {
            int row = nt * 16 + l15 + k;
            int pc = (kk * 4 + quad) ^ (row & 7);
            bf16x8 bfr = ld8(&cfs[row][pc * 8]);
#pragma unroll
            for (int m = 0; m < 4; ++m)
              acc[m][s] = __builtin_amdgcn_mfma_f32_16x16x32_bf16(af[m], bfr, acc[m][s], 0, 0, 0);
          }
        }
      }
    }
  }

#pragma unroll
  for (int s = 0; s < 6; ++s) {
    int nt = wv + 4 * s;
    if (nt < 22) {
      int p = nt * 16 + l15;
      int q = p / 44, x = p % 44;
      if (x >= 4 && x < 40) {
        int bp = r0 + q;
#pragma unroll
        for (int m = 0; m < 4; ++m) {
          int o0 = m * 16 + quad * 4;
          unsigned short pk[4];
#pragma unroll
          for (int rg = 0; rg < 4; ++rg) {
            float v = acc[m][s][rg] * kscale[o0 + rg] + kshift[o0 + rg];
            pk[rg] = f2bf(v > 0.f ? v : 0.f);
          }
          *(uint2*)(catf + ((size_t)bp * 36 + (x - 4)) * 64 + o0) = *(uint2*)pk;
        }
      }
    }
  }
}

// ---------------------------------------------------------------------------
// K1c: fc GEMM (M=64, K=2304, N=12288) + bias + LayerNorm + relu.
// Block = 64 rois; wave w owns n-tile w (16 rois), holds all 4 m-tiles.
// ---------------------------------------------------------------------------
__global__ __launch_bounds__(256)
void k_fc(const unsigned short* __restrict__ catf,   // [12288][36][64]
          const unsigned short* __restrict__ fw,     // [64][2304] (j-major K)
          const float* __restrict__ fc_b,
          const float* __restrict__ ln_g, const float* __restrict__ ln_b,
          float* __restrict__ roi_fc) {
  __shared__ __align__(16) float fcb[64][68];
  int tid = threadIdx.x, wv = tid >> 6, lane = tid & 63, l15 = lane & 15, quad = lane >> 4;
  int nbase = blockIdx.x * 64 + wv * 16;

  f32x4 acc[4];
#pragma unroll
  for (int m = 0; m < 4; ++m) acc[m] = (f32x4)0.f;

  for (int ks = 0; ks < 72; ++ks) {
    int j = ks >> 1, ch = (ks & 1) * 32;
    bf16x8 bfr = ld8(catf + ((size_t)(nbase + l15) * 36 + j) * 64 + ch + quad * 8);
#pragma unroll
    for (int m = 0; m < 4; ++m) {
      bf16x8 af = ld8(fw + (size_t)(m * 16 + l15) * 2304 + ks * 32 + quad * 8);
      acc[m] = __builtin_amdgcn_mfma_f32_16x16x32_bf16(af, bfr, acc[m], 0, 0, 0);
    }
  }

#pragma unroll
  for (int m = 0; m < 4; ++m) {
    f32x4 v;
#pragma unroll
    for (int rg = 0; rg < 4; ++rg) v[rg] = acc[m][rg] + fc_b[m * 16 + quad * 4 + rg];
    *(f32x4*)&fcb[wv * 16 + l15][m * 16 + quad * 4] = v;
  }
  __syncthreads();

  for (int rr = 0; rr < 16; ++rr) {
    int rl = wv * 16 + rr;
    float y = fcb[rl][lane];
    float s = y;
#pragma unroll
    for (int off = 32; off > 0; off >>= 1) s += __shfl_xor(s, off, 64);
    float mu = s * (1.f / 64.f);
    float d = y - mu;
    float v2 = d * d;
#pragma unroll
    for (int off = 32; off > 0; off >>= 1) v2 += __shfl_xor(v2, off, 64);
    float var = v2 * (1.f / 64.f);
    float r = d / sqrtf(var + 1e-5f) * ln_g[lane] + ln_b[lane];
    roi_fc[(size_t)(blockIdx.x * 64 + rl) * 64 + lane] = r > 0.f ? r : 0.f;
  }
}

// ---------------------------------------------------------------------------
// K3: attention + MLP heads + tan epilogue + cascade update (round-1 verified).
// ---------------------------------------------------------------------------
__global__ __launch_bounds__(256)
void k_att(const float* __restrict__ roi_fc,
           const float* __restrict__ keyf, const float* __restrict__ value,
           const float* __restrict__ fq_w, const float* __restrict__ fq_b,
           const float* __restrict__ attW_w, const float* __restrict__ attW_b,
           const float* __restrict__ cls_mlp_w, const float* __restrict__ cls_mlp_b,
           const float* __restrict__ reg_mlp_w, const float* __restrict__ reg_mlp_b,
           const float* __restrict__ cls_head_w, const float* __restrict__ cls_head_b,
           const float* __restrict__ reg_head_w, const float* __restrict__ reg_head_b,
           const float* __restrict__ priors_cur,
           float* __restrict__ priors_next,
           float* __restrict__ preds) {
  int bp = blockIdx.x;
  int b = bp / PP, p = bp % PP;
  int tid = threadIdx.x;
  __shared__ float rf_s[64], q_s[64], x_s[64], h1c[64], h1r[64], h2c[64], h2r[64];
  __shared__ float sim[256], red[256];
  __shared__ float cls_s[2], reg_s[76];

  if (tid < 64) {
    float rf = roi_fc[(size_t)bp * 64 + tid];
    rf_s[tid] = rf;
    float q = rf * fq_w[p] + fq_b[p];
    q_s[tid] = q > 0.f ? q : 0.f;
  }
  __syncthreads();

  float sc = -1e30f;
  if (tid < 250) {
    const float* kcol = keyf + (size_t)b * 64 * 250 + tid;
    float acc = 0.f;
#pragma unroll 8
    for (int c = 0; c < 64; ++c) acc += q_s[c] * kcol[c * 250];
    sc = acc * 0.125f;
  }
  red[tid] = sc;
  __syncthreads();
  for (int off = 128; off > 0; off >>= 1) {
    if (tid < off) red[tid] = fmaxf(red[tid], red[tid + off]);
    __syncthreads();
  }
  float m = red[0];
  __syncthreads();
  float e = (tid < 250) ? expf(sc - m) : 0.f;
  red[tid] = e;
  __syncthreads();
  for (int off = 128; off > 0; off >>= 1) {
    if (tid < off) red[tid] += red[tid + off];
    __syncthreads();
  }
  float ssum = red[0];
  sim[tid] = e / ssum;
  __syncthreads();

  if (tid < 64) {
    const float* vrow = value + ((size_t)b * 64 + tid) * 250;
    float acc = 0.f;
    for (int k = 0; k < 250; ++k) acc += sim[k] * vrow[k];
    float ctx = acc * attW_w[p] + attW_b[p];
    x_s[tid] = rf_s[tid] + ctx;
  }
  __syncthreads();

  if (tid < 64) {
    int o = tid;
    float ac = cls_mlp_b[o], ar = reg_mlp_b[o];
    const float* wc = cls_mlp_w + o * 64;
    const float* wr = reg_mlp_w + o * 64;
    for (int c = 0; c < 64; ++c) { float xv = x_s[c]; ac += xv * wc[c]; ar += xv * wr[c]; }
    h1c[o] = ac > 0.f ? ac : 0.f;
    h1r[o] = ar > 0.f ? ar : 0.f;
  }
  __syncthreads();
  if (tid < 64) {
    int o = tid;
    float ac = cls_mlp_b[64 + o], ar = reg_mlp_b[64 + o];
    const float* wc = cls_mlp_w + 4096 + o * 64;
    const float* wr = reg_mlp_w + 4096 + o * 64;
    for (int c = 0; c < 64; ++c) { ac += h1c[c] * wc[c]; ar += h1r[c] * wr[c]; }
    h2c[o] = ac > 0.f ? ac : 0.f;
    h2r[o] = ar > 0.f ? ar : 0.f;
  }
  __syncthreads();
  if (tid < 2) {
    float a = cls_head_b[tid];
    const float* w = cls_head_w + tid * 64;
    for (int c = 0; c < 64; ++c) a += h2c[c] * w[c];
    cls_s[tid] = a;
  }
  if (tid >= 64 && tid < 64 + 76) {
    int o = tid - 64;
    float a = reg_head_b[o];
    const float* w = reg_head_w + o * 64;
    for (int c = 0; c < 64; ++c) a += h2r[c] * w[c];
    reg_s[o] = a;
  }
  __syncthreads();

  const float* pc = priors_cur + (size_t)bp * 78;
  float* po = preds + (size_t)bp * 78;
  float p0 = pc[2] + reg_s[0];
  float p1 = pc[3] + reg_s[1];
  float p2 = pc[4] + reg_s[2];
  if (tid == 0) {
    po[0] = cls_s[0]; po[1] = cls_s[1];
    po[2] = p0; po[3] = p1; po[4] = p2;
    po[5] = reg_s[3];
    if (priors_next) {
      float* pn = priors_next + (size_t)bp * 78;
      pn[0] = cls_s[0]; pn[1] = cls_s[1];
      pn[2] = p0; pn[3] = p1; pn[4] = p2; pn[5] = reg_s[3];
    }
  }
  if (tid < 72) {
    float py = 1.0f - (float)tid / 71.0f;
    float t = tanf(p2 * PI_F + 1e-5f);
    float offs = (p1 * 639.0f + (1.0f - py - p0) * 512.0f / t) / 639.0f;
    po[6 + tid] = offs + reg_s[4 + tid];
    if (priors_next) priors_next[(size_t)bp * 78 + 6 + tid] = offs;
  }
}

// ---------------------------------------------------------------------------
extern "C" void kernel_launch(void* const* d_in, const int* in_sizes, int n_in,
                              void* d_out, int out_size, void* d_ws, size_t ws_size,
                              hipStream_t stream) {
  (void)in_sizes; (void)n_in; (void)out_size; (void)ws_size;
  const float* feat[3] = {(const float*)d_in[0], (const float*)d_in[1], (const float*)d_in[2]};
  const float* priors      = (const float*)d_in[3];
  const float* convs_w     = (const float*)d_in[4];
  const float* convs_scale = (const float*)d_in[5];
  const float* convs_shift = (const float*)d_in[6];
  const float* cat_w[3]    = {(const float*)d_in[7], (const float*)d_in[8], (const float*)d_in[9]};
  const float* cat_scale   = (const float*)d_in[10];
  const float* cat_shift   = (const float*)d_in[11];
  const float* fkey_w      = (const float*)d_in[12];
  const float* fkey_scale  = (const float*)d_in[13];
  const float* fkey_shift  = (const float*)d_in[14];
  const float* fval_w      = (const float*)d_in[15];
  const float* fval_b      = (const float*)d_in[16];
  const float* fq_w        = (const float*)d_in[17];
  const float* fq_b        = (const float*)d_in[18];
  const float* attW_w      = (const float*)d_in[19];
  const float* attW_b      = (const float*)d_in[20];
  const float* fc_w        = (const float*)d_in[21];
  const float* fc_b        = (const float*)d_in[22];
  const float* ln_g        = (const float*)d_in[23];
  const float* ln_b        = (const float*)d_in[24];
  const float* cls_mlp_w   = (const float*)d_in[25];
  const float* cls_mlp_b   = (const float*)d_in[26];
  const float* reg_mlp_w   = (const float*)d_in[27];
  const float* reg_mlp_b   = (const float*)d_in[28];
  const float* cls_head_w  = (const float*)d_in[29];
  const float* cls_head_b  = (const float*)d_in[30];
  const float* reg_head_w  = (const float*)d_in[31];
  const float* reg_head_b  = (const float*)d_in[32];
  float* out = (float*)d_out;

  char* wp = (char*)d_ws;
  auto alloc = [&](size_t bytes) { char* r = wp; wp += (bytes + 255) & ~(size_t)255; return r; };

  float* priA   = (float*)alloc((size_t)BB * PP * 78 * 4);
  float* priB   = (float*)alloc((size_t)BB * PP * 78 * 4);
  float* roi_fc = (float*)alloc((size_t)BB * PP * 64 * 4);
  float* keyb   = (float*)alloc((size_t)BB * 64 * 250 * 4);
  float* valb   = (float*)alloc((size_t)BB * 64 * 250 * 4);
  unsigned short* Wr   = (unsigned short*)alloc(82944ull * 2);
  unsigned short* Wc   = (unsigned short*)alloc(221184ull * 2);
  unsigned short* fw   = (unsigned short*)alloc(147456ull * 2);
  unsigned short* cfg  = (unsigned short*)alloc(3ull * 12288 * 36 * 48 * 2);
  unsigned short* catf = (unsigned short*)alloc(12288ull * 36 * 64 * 2);

  const int HW[3][2] = {{64, 80}, {32, 40}, {16, 20}};
  const size_t wcoff[3] = {0, 36864, 110592};

  k_init_priors<<<dim3((BB * PP * 78 + 255) / 256), dim3(256), 0, stream>>>(priors, priA);
  k_repack<<<dim3((451584 + 255) / 256), dim3(256), 0, stream>>>(
      convs_w, cat_w[0], cat_w[1], cat_w[2], fc_w, Wr, Wc, fw);

  float* pcur = priA;
  float* pnext = priB;
  for (int s = 0; s < 3; ++s) {
    int H = HW[s][0], W = HW[s][1];
    k_keyval<<<dim3(BB * 250), dim3(64), 0, stream>>>(
        feat[s], H, W, fkey_w, fkey_scale, fkey_shift, fval_w, fval_b, keyb, valb);

    if (s == 0) {
      k_gatherconv<0><<<dim3(1536), dim3(256), 0, stream>>>(
          feat[0], pcur, Wr + 0 * 27648, convs_scale + 0, convs_shift + 0,
          cfg + 0ull * 12288 * 36 * 48);
      k_cat<0><<<dim3(1536), dim3(256), 0, stream>>>(
          cfg, Wc + wcoff[0], cat_scale + 0, cat_shift + 0, catf);
    } else if (s == 1) {
      k_gatherconv<1><<<dim3(1536), dim3(256), 0, stream>>>(
          feat[1], pcur, Wr + 1 * 27648, convs_scale + 48, convs_shift + 48,
          cfg + 1ull * 12288 * 36 * 48);
      k_cat<1><<<dim3(1536), dim3(256), 0, stream>>>(
          cfg, Wc + wcoff[1], cat_scale + 64, cat_shift + 64, catf);
    } else {
      k_gatherconv<2><<<dim3(1536), dim3(256), 0, stream>>>(
          feat[2], pcur, Wr + 2 * 27648, convs_scale + 96, convs_shift + 96,
          cfg + 2ull * 12288 * 36 * 48);
      k_cat<2><<<dim3(1536), dim3(256), 0, stream>>>(
          cfg, Wc + wcoff[2], cat_scale + 128, cat_shift + 128, catf);
    }

    k_fc<<<dim3(192), dim3(256), 0, stream>>>(catf, fw, fc_b, ln_g, ln_b, roi_fc);

    k_att<<<dim3(BB * PP), dim3(256), 0, stream>>>(
        roi_fc, keyb, valb, fq_w, fq_b, attW_w, attW_b,
        cls_mlp_w, cls_mlp_b, reg_mlp_w, reg_mlp_b,
        cls_head_w, cls_head_b, reg_head_w, reg_head_b,
        pcur, (s < 2) ? pnext : (float*)nullptr,
        out + (size_t)s * BB * PP * 78);

    float* tmp = pcur; pcur = pnext; pnext = tmp;
  }
}

// Round 3
// 2025.538 us; speedup vs baseline: 4.3212x; 1.5046x over previous
//
#include <hip/hip_runtime.h>
#include <hip/hip_bf16.h>

#define BB 64
#define PP 192
#define SS 36
#define PI_F 3.14159265358979323846f

typedef __attribute__((ext_vector_type(8))) __bf16 bf16x8;
typedef __attribute__((ext_vector_type(4))) float f32x4;
typedef __attribute__((ext_vector_type(8))) unsigned short us8;

__device__ inline unsigned short f2bf(float f) {
  unsigned int u = __builtin_bit_cast(unsigned int, f);
  unsigned int r = (u + 0x7FFFu + ((u >> 16) & 1u)) >> 16;
  return (unsigned short)r;
}

__device__ inline float bf2f(unsigned short u) {
  return __builtin_bit_cast(float, (unsigned int)u << 16);
}

__device__ inline bf16x8 ld8(const unsigned short* p) {
  us8 v = *(const us8*)p;
  return __builtin_bit_cast(bf16x8, v);
}

// ---------------------------------------------------------------------------
// K0: broadcast priors (P,78) -> (B,P,78)
// ---------------------------------------------------------------------------
__global__ __launch_bounds__(256)
void k_init_priors(const float* __restrict__ priors, float* __restrict__ out) {
  int idx = blockIdx.x * 256 + threadIdx.x;
  if (idx < BB * PP * 78) out[idx] = priors[idx % (PP * 78)];
}

// ---------------------------------------------------------------------------
// K0b: fmap [B][C][H][W] fp32 -> fmT [B][H*W][C] bf16 (pixel-major).
// 64ch x 64pos LDS tile; coalesced read + coalesced write.
// ---------------------------------------------------------------------------
__global__ __launch_bounds__(256)
void k_transpose(const float* __restrict__ fmap, int HW, int tiles_per_b,
                 unsigned short* __restrict__ fmT) {
  __shared__ unsigned short Ls[64][66];
  int b = blockIdx.x / tiles_per_b;
  int p0 = (blockIdx.x % tiles_per_b) * 64;
  int tid = threadIdx.x;
  for (int idx = tid; idx < 4096; idx += 256) {
    int c = idx >> 6, pos = idx & 63;
    Ls[c][pos] = f2bf(fmap[((size_t)b * 64 + c) * HW + p0 + pos]);
  }
  __syncthreads();
  for (int idx = tid; idx < 4096; idx += 256) {
    int pos = idx >> 6, c = idx & 63;
    fmT[((size_t)b * HW + p0 + pos) * 64 + c] = Ls[c][pos];
  }
}

// ---------------------------------------------------------------------------
// Repack weights to bf16 MFMA-A layouts (runs every launch; cheap).
// ---------------------------------------------------------------------------
__global__ __launch_bounds__(256)
void k_repack(const float* __restrict__ cw,
              const float* __restrict__ c0, const float* __restrict__ c1,
              const float* __restrict__ c2, const float* __restrict__ fcw,
              unsigned short* __restrict__ Wr, unsigned short* __restrict__ Wc,
              unsigned short* __restrict__ fw) {
  int idx = blockIdx.x * 256 + threadIdx.x;
  if (idx < 82944) {
    int c = idx & 63; int t = idx >> 6; int o = t % 48; t /= 48;
    int k = t % 9; int s = t / 9;
    Wr[idx] = f2bf(cw[((size_t)(s * 48 + o) * 64 + c) * 9 + k]);
  } else if (idx < 82944 + 221184) {
    int r = idx - 82944;
    int s, base, NC;
    if (r < 36864)            { s = 0; base = 0;      NC = 1; }
    else if (r < 110592)      { s = 1; base = 36864;  NC = 2; }
    else                      { s = 2; base = 110592; NC = 3; }
    int q = r - base;
    int c = q & 63; int t = q >> 6; int o = t & 63; t >>= 6;
    int k = t % 9; int i = t / 9;
    const float* src = (s == 0) ? c0 : (s == 1) ? c1 : c2;
    float v = (c < 48) ? src[((size_t)o * (NC * 48) + i * 48 + c) * 9 + k] : 0.f;
    Wc[r] = f2bf(v);
  } else if (idx < 82944 + 221184 + 147456) {
    int q = idx - (82944 + 221184);
    int h = q / 2304; int kp = q % 2304; int j = kp >> 6; int c = kp & 63;
    fw[q] = f2bf(fcw[(size_t)h * 2304 + c * 36 + j]);
  }
}

// ---------------------------------------------------------------------------
// K2: key/value maps, reading pixel-major bf16 fmT (coalesced).
// ---------------------------------------------------------------------------
__global__ __launch_bounds__(64)
void k_keyval(const unsigned short* __restrict__ fmT, int H, int W,
              const float* __restrict__ fkey_w, const float* __restrict__ fkey_scale,
              const float* __restrict__ fkey_shift,
              const float* __restrict__ fval_w, const float* __restrict__ fval_b,
              float* __restrict__ keyf, float* __restrict__ value) {
  int b = blockIdx.x / 250;
  int k = blockIdx.x % 250;
  int r = k / 25, c2 = k % 25;
  int iy = (r * H) / 10, ix = (c2 * W) / 25;
  __shared__ float f[64];
  int o = threadIdx.x;
  f[o] = bf2f(fmT[((size_t)b * H * W + iy * W + ix) * 64 + o]);
  __syncthreads();
  float ak = 0.f, av = 0.f;
#pragma unroll 8
  for (int c = 0; c < 64; ++c) {
    float fv = f[c];
    ak += fv * fkey_w[o * 64 + c];
    av += fv * fval_w[o * 64 + c];
  }
  float kf = ak * fkey_scale[o] + fkey_shift[o];
  keyf[(size_t)(b * 64 + o) * 250 + k] = kf > 0.f ? kf : 0.f;
  value[(size_t)(b * 64 + o) * 250 + k] = av + fval_b[o];
}

// ---------------------------------------------------------------------------
// K1a: fused gather + conv_s (MFMA). Block = 8 rois. Gather now reads
// pixel-major bf16 fmT: 8 lanes x us8 (16B) per position tap = coalesced.
// ---------------------------------------------------------------------------
template <int STAGE>
__global__ __launch_bounds__(256)
void k_gatherconv(const unsigned short* __restrict__ fmT,
                  const float* __restrict__ priors_cur,
                  const unsigned short* __restrict__ Wr,   // [9][48][64] this stage
                  const float* __restrict__ cscale, const float* __restrict__ cshift,
                  unsigned short* __restrict__ cfg) {      // [12288][36][48]
  constexpr int H = (STAGE == 0) ? 64 : (STAGE == 1) ? 32 : 16;
  constexpr int W = (STAGE == 0) ? 80 : (STAGE == 1) ? 40 : 20;
  constexpr int HW = H * W;

  __shared__ float posx[8][36], posy[8][36];
  __shared__ __align__(16) unsigned short Xs[360][64];

  int tid = threadIdx.x;
  int r0 = blockIdx.x * 8;

  for (int idx = tid; idx < 288; idx += 256) {
    int q = idx / 36, j = idx % 36;
    int bp = r0 + q;
    int k = 35 - j;
    int sx = (int)(((float)k / 35.0f) * 71.0f);
    float px = priors_cur[(size_t)bp * 78 + 6 + sx];
    posx[q][j] = px * (float)(W - 1);
    float fy = 1.0f - (float)sx / 71.0f;
    posy[q][j] = fy * (float)(H - 1);
  }
  __syncthreads();

  // gather: each lane handles 8 channels of one packed row
  for (int idx = tid; idx < 360 * 8; idx += 256) {
    int row = idx >> 3, ch8 = idx & 7;
    int p = row - 4;
    unsigned short pk[8] = {0, 0, 0, 0, 0, 0, 0, 0};
    if (p >= 0 && p < 352) {
      int q = p / 44, x = p % 44;
      if (x >= 4 && x < 40) {
        int j = x - 4;
        int b = (r0 + q) / PP;
        float fx = posx[q][j];
        float fy = posy[q][j];
        float x0 = floorf(fx), y0 = floorf(fy);
        float wx = fx - x0, wy = fy - y0;
        float xs2[2] = {x0, x0 + 1.f};
        float ys2[2] = {y0, y0 + 1.f};
        float wxs[2] = {1.f - wx, wx};
        float wys[2] = {1.f - wy, wy};
        float accf[8] = {0.f, 0.f, 0.f, 0.f, 0.f, 0.f, 0.f, 0.f};
#pragma unroll
        for (int ty = 0; ty < 2; ++ty)
#pragma unroll
          for (int tx = 0; tx < 2; ++tx) {
            float xf = xs2[tx], yf = ys2[ty];
            bool v = (xf >= 0.f) && (xf <= (float)(W - 1)) &&
                     (yf >= 0.f) && (yf <= (float)(H - 1));
            int xi = (int)fminf(fmaxf(xf, 0.f), (float)(W - 1));
            int yi = (int)fminf(fmaxf(yf, 0.f), (float)(H - 1));
            float wgt = v ? (wxs[tx] * wys[ty]) : 0.f;
            const us8 vv = *(const us8*)(fmT + ((size_t)b * HW + yi * W + xi) * 64 + ch8 * 8);
#pragma unroll
            for (int e = 0; e < 8; ++e) accf[e] += wgt * bf2f(vv[e]);
          }
#pragma unroll
        for (int e = 0; e < 8; ++e) pk[e] = f2bf(accf[e]);
      }
    }
    int pc = ch8 ^ (row & 7);
    *(us8*)&Xs[row][pc * 8] = *(us8*)pk;
  }
  __syncthreads();

  int wv = tid >> 6, lane = tid & 63, l15 = lane & 15, quad = lane >> 4;
  f32x4 acc[3][6];
#pragma unroll
  for (int m = 0; m < 3; ++m)
#pragma unroll
    for (int s = 0; s < 6; ++s) acc[m][s] = (f32x4)0.f;

  for (int k = 0; k < 9; ++k) {
#pragma unroll
    for (int kk = 0; kk < 2; ++kk) {
      bf16x8 af[3];
#pragma unroll
      for (int m = 0; m < 3; ++m)
        af[m] = ld8(Wr + ((size_t)(k * 48 + m * 16 + l15)) * 64 + kk * 32 + quad * 8);
#pragma unroll
      for (int s = 0; s < 6; ++s) {
        int nt = wv + 4 * s;
        if (nt < 22) {
          int row = nt * 16 + l15 + k;
          int pc = (kk * 4 + quad) ^ (row & 7);
          bf16x8 bfr = ld8(&Xs[row][pc * 8]);
#pragma unroll
          for (int m = 0; m < 3; ++m)
            acc[m][s] = __builtin_amdgcn_mfma_f32_16x16x32_bf16(af[m], bfr, acc[m][s], 0, 0, 0);
        }
      }
    }
  }

#pragma unroll
  for (int s = 0; s < 6; ++s) {
    int nt = wv + 4 * s;
    if (nt < 22) {
      int p = nt * 16 + l15;
      int q = p / 44, x = p % 44;
      if (x >= 4 && x < 40) {
        int bp = r0 + q;
#pragma unroll
        for (int m = 0; m < 3; ++m) {
          int o0 = m * 16 + quad * 4;
          unsigned short pk[4];
#pragma unroll
          for (int rg = 0; rg < 4; ++rg) {
            float v = acc[m][s][rg] * cscale[o0 + rg] + cshift[o0 + rg];
            pk[rg] = f2bf(v > 0.f ? v : 0.f);
          }
          *(uint2*)(cfg + ((size_t)bp * 36 + (x - 4)) * 48 + o0) = *(uint2*)pk;
        }
      }
    }
  }
}

// ---------------------------------------------------------------------------
// K1b: cat conv (MFMA), accumulating over stage groups i=0..STAGE.
// ---------------------------------------------------------------------------
template <int STAGE>
__global__ __launch_bounds__(256)
void k_cat(const unsigned short* __restrict__ cfg_all,
           const unsigned short* __restrict__ Wc,
           const float* __restrict__ kscale, const float* __restrict__ kshift,
           unsigned short* __restrict__ catf) {
  constexpr int NC = STAGE + 1;
  __shared__ __align__(16) unsigned short cfs[360][64];
  int tid = threadIdx.x;
  int r0 = blockIdx.x * 8;
  int wv = tid >> 6, lane = tid & 63, l15 = lane & 15, quad = lane >> 4;

  f32x4 acc[4][6];
#pragma unroll
  for (int m = 0; m < 4; ++m)
#pragma unroll
    for (int s = 0; s < 6; ++s) acc[m][s] = (f32x4)0.f;

#pragma unroll
  for (int i = 0; i < NC; ++i) {
    __syncthreads();
    for (int idx = tid; idx < 360 * 8; idx += 256) {
      int row = idx >> 3, ch = idx & 7;
      int p = row - 4;
      us8 v = (us8)(unsigned short)0;
      if (p >= 0 && p < 352 && ch < 6) {
        int q = p / 44, x = p % 44;
        if (x >= 4 && x < 40) {
          const unsigned short* src = cfg_all + (size_t)i * (12288ull * 36 * 48) +
                                      ((size_t)(r0 + q) * 36 + (x - 4)) * 48 + ch * 8;
          v = *(const us8*)src;
        }
      }
      int pc = ch ^ (row & 7);
      *(us8*)&cfs[row][pc * 8] = v;
    }
    __syncthreads();

    for (int k = 0; k < 9; ++k) {
#pragma unroll
      for (int kk = 0; kk < 2; ++kk) {
        bf16x8 af[4];
#pragma unroll
        for (int m = 0; m < 4; ++m)
          af[m] = ld8(Wc + (((size_t)i * 9 + k) * 64 + m * 16 + l15) * 64 + kk * 32 + quad * 8);
#pragma unroll
        for (int s = 0; s < 6; ++s) {
          int nt = wv + 4 * s;
          if (nt < 22) {
            int row = nt * 16 + l15 + k;
            int pc = (kk * 4 + quad) ^ (row & 7);
            bf16x8 bfr = ld8(&cfs[row][pc * 8]);
#pragma unroll
            for (int m = 0; m < 4; ++m)
              acc[m][s] = __builtin_amdgcn_mfma_f32_16x16x32_bf16(af[m], bfr, acc[m][s], 0, 0, 0);
          }
        }
      }
    }
  }

#pragma unroll
  for (int s = 0; s < 6; ++s) {
    int nt = wv + 4 * s;
    if (nt < 22) {
      int p = nt * 16 + l15;
      int q = p / 44, x = p % 44;
      if (x >= 4 && x < 40) {
        int bp = r0 + q;
#pragma unroll
        for (int m = 0; m < 4; ++m) {
          int o0 = m * 16 + quad * 4;
          unsigned short pk[4];
#pragma unroll
          for (int rg = 0; rg < 4; ++rg) {
            float v = acc[m][s][rg] * kscale[o0 + rg] + kshift[o0 + rg];
            pk[rg] = f2bf(v > 0.f ? v : 0.f);
          }
          *(uint2*)(catf + ((size_t)bp * 36 + (x - 4)) * 64 + o0) = *(uint2*)pk;
        }
      }
    }
  }
}

// ---------------------------------------------------------------------------
// K1c: fc GEMM (M=64, K=2304, N=12288) + bias + LayerNorm + relu.
// ---------------------------------------------------------------------------
__global__ __launch_bounds__(256)
void k_fc(const unsigned short* __restrict__ catf,
          const unsigned short* __restrict__ fw,
          const float* __restrict__ fc_b,
          const float* __restrict__ ln_g, const float* __restrict__ ln_b,
          float* __restrict__ roi_fc) {
  __shared__ __align__(16) float fcb[64][68];
  int tid = threadIdx.x, wv = tid >> 6, lane = tid & 63, l15 = lane & 15, quad = lane >> 4;
  int nbase = blockIdx.x * 64 + wv * 16;

  f32x4 acc[4];
#pragma unroll
  for (int m = 0; m < 4; ++m) acc[m] = (f32x4)0.f;

  for (int ks = 0; ks < 72; ++ks) {
    int j = ks >> 1, ch = (ks & 1) * 32;
    bf16x8 bfr = ld8(catf + ((size_t)(nbase + l15) * 36 + j) * 64 + ch + quad * 8);
#pragma unroll
    for (int m = 0; m < 4; ++m) {
      bf16x8 af = ld8(fw + (size_t)(m * 16 + l15) * 2304 + ks * 32 + quad * 8);
      acc[m] = __builtin_amdgcn_mfma_f32_16x16x32_bf16(af, bfr, acc[m], 0, 0, 0);
    }
  }

#pragma unroll
  for (int m = 0; m < 4; ++m) {
    f32x4 v;
#pragma unroll
    for (int rg = 0; rg < 4; ++rg) v[rg] = acc[m][rg] + fc_b[m * 16 + quad * 4 + rg];
    *(f32x4*)&fcb[wv * 16 + l15][m * 16 + quad * 4] = v;
  }
  __syncthreads();

  for (int rr = 0; rr < 16; ++rr) {
    int rl = wv * 16 + rr;
    float y = fcb[rl][lane];
    float s = y;
#pragma unroll
    for (int off = 32; off > 0; off >>= 1) s += __shfl_xor(s, off, 64);
    float mu = s * (1.f / 64.f);
    float d = y - mu;
    float v2 = d * d;
#pragma unroll
    for (int off = 32; off > 0; off >>= 1) v2 += __shfl_xor(v2, off, 64);
    float var = v2 * (1.f / 64.f);
    float r = d / sqrtf(var + 1e-5f) * ln_g[lane] + ln_b[lane];
    roi_fc[(size_t)(blockIdx.x * 64 + rl) * 64 + lane] = r > 0.f ? r : 0.f;
  }
}

// ---------------------------------------------------------------------------
// K3: attention + MLP heads + tan epilogue + cascade update.
// ---------------------------------------------------------------------------
__global__ __launch_bounds__(256)
void k_att(const float* __restrict__ roi_fc,
           const float* __restrict__ keyf, const float* __restrict__ value,
           const float* __restrict__ fq_w, const float* __restrict__ fq_b,
           const float* __restrict__ attW_w, const float* __restrict__ attW_b,
           const float* __restrict__ cls_mlp_w, const float* __restrict__ cls_mlp_b,
           const float* __restrict__ reg_mlp_w, const float* __restrict__ reg_mlp_b,
           const float* __restrict__ cls_head_w, const float* __restrict__ cls_head_b,
           const float* __restrict__ reg_head_w, const float* __restrict__ reg_head_b,
           const float* __restrict__ priors_cur,
           float* __restrict__ priors_next,
           float* __restrict__ preds) {
  int bp = blockIdx.x;
  int b = bp / PP, p = bp % PP;
  int tid = threadIdx.x;
  __shared__ float rf_s[64], q_s[64], x_s[64], h1c[64], h1r[64], h2c[64], h2r[64];
  __shared__ float sim[256], red[256];
  __shared__ float cls_s[2], reg_s[76];

  if (tid < 64) {
    float rf = roi_fc[(size_t)bp * 64 + tid];
    rf_s[tid] = rf;
    float q = rf * fq_w[p] + fq_b[p];
    q_s[tid] = q > 0.f ? q : 0.f;
  }
  __syncthreads();

  float sc = -1e30f;
  if (tid < 250) {
    const float* kcol = keyf + (size_t)b * 64 * 250 + tid;
    float acc = 0.f;
#pragma unroll 8
    for (int c = 0; c < 64; ++c) acc += q_s[c] * kcol[c * 250];
    sc = acc * 0.125f;
  }
  red[tid] = sc;
  __syncthreads();
  for (int off = 128; off > 0; off >>= 1) {
    if (tid < off) red[tid] = fmaxf(red[tid], red[tid + off]);
    __syncthreads();
  }
  float m = red[0];
  __syncthreads();
  float e = (tid < 250) ? expf(sc - m) : 0.f;
  red[tid] = e;
  __syncthreads();
  for (int off = 128; off > 0; off >>= 1) {
    if (tid < off) red[tid] += red[tid + off];
    __syncthreads();
  }
  float ssum = red[0];
  sim[tid] = e / ssum;
  __syncthreads();

  if (tid < 64) {
    const float* vrow = value + ((size_t)b * 64 + tid) * 250;
    float acc = 0.f;
    for (int k = 0; k < 250; ++k) acc += sim[k] * vrow[k];
    float ctx = acc * attW_w[p] + attW_b[p];
    x_s[tid] = rf_s[tid] + ctx;
  }
  __syncthreads();

  if (tid < 64) {
    int o = tid;
    float ac = cls_mlp_b[o], ar = reg_mlp_b[o];
    const float* wc = cls_mlp_w + o * 64;
    const float* wr = reg_mlp_w + o * 64;
    for (int c = 0; c < 64; ++c) { float xv = x_s[c]; ac += xv * wc[c]; ar += xv * wr[c]; }
    h1c[o] = ac > 0.f ? ac : 0.f;
    h1r[o] = ar > 0.f ? ar : 0.f;
  }
  __syncthreads();
  if (tid < 64) {
    int o = tid;
    float ac = cls_mlp_b[64 + o], ar = reg_mlp_b[64 + o];
    const float* wc = cls_mlp_w + 4096 + o * 64;
    const float* wr = reg_mlp_w + 4096 + o * 64;
    for (int c = 0; c < 64; ++c) { ac += h1c[c] * wc[c]; ar += h1r[c] * wr[c]; }
    h2c[o] = ac > 0.f ? ac : 0.f;
    h2r[o] = ar > 0.f ? ar : 0.f;
  }
  __syncthreads();
  if (tid < 2) {
    float a = cls_head_b[tid];
    const float* w = cls_head_w + tid * 64;
    for (int c = 0; c < 64; ++c) a += h2c[c] * w[c];
    cls_s[tid] = a;
  }
  if (tid >= 64 && tid < 64 + 76) {
    int o = tid - 64;
    float a = reg_head_b[o];
    const float* w = reg_head_w + o * 64;
    for (int c = 0; c < 64; ++c) a += h2r[c] * w[c];
    reg_s[o] = a;
  }
  __syncthreads();

  const float* pc = priors_cur + (size_t)bp * 78;
  float* po = preds + (size_t)bp * 78;
  float p0 = pc[2] + reg_s[0];
  float p1 = pc[3] + reg_s[1];
  float p2 = pc[4] + reg_s[2];
  if (tid == 0) {
    po[0] = cls_s[0]; po[1] = cls_s[1];
    po[2] = p0; po[3] = p1; po[4] = p2;
    po[5] = reg_s[3];
    if (priors_next) {
      float* pn = priors_next + (size_t)bp * 78;
      pn[0] = cls_s[0]; pn[1] = cls_s[1];
      pn[2] = p0; pn[3] = p1; pn[4] = p2; pn[5] = reg_s[3];
    }
  }
  if (tid < 72) {
    float py = 1.0f - (float)tid / 71.0f;
    float t = tanf(p2 * PI_F + 1e-5f);
    float offs = (p1 * 639.0f + (1.0f - py - p0) * 512.0f / t) / 639.0f;
    po[6 + tid] = offs + reg_s[4 + tid];
    if (priors_next) priors_next[(size_t)bp * 78 + 6 + tid] = offs;
  }
}

// ---------------------------------------------------------------------------
extern "C" void kernel_launch(void* const* d_in, const int* in_sizes, int n_in,
                              void* d_out, int out_size, void* d_ws, size_t ws_size,
                              hipStream_t stream) {
  (void)in_sizes; (void)n_in; (void)out_size; (void)ws_size;
  const float* feat[3] = {(const float*)d_in[0], (const float*)d_in[1], (const float*)d_in[2]};
  const float* priors      = (const float*)d_in[3];
  const float* convs_w     = (const float*)d_in[4];
  const float* convs_scale = (const float*)d_in[5];
  const float* convs_shift = (const float*)d_in[6];
  const float* cat_w[3]    = {(const float*)d_in[7], (const float*)d_in[8], (const float*)d_in[9]};
  const float* cat_scale   = (const float*)d_in[10];
  const float* cat_shift   = (const float*)d_in[11];
  const float* fkey_w      = (const float*)d_in[12];
  const float* fkey_scale  = (const float*)d_in[13];
  const float* fkey_shift  = (const float*)d_in[14];
  const float* fval_w      = (const float*)d_in[15];
  const float* fval_b      = (const float*)d_in[16];
  const float* fq_w        = (const float*)d_in[17];
  const float* fq_b        = (const float*)d_in[18];
  const float* attW_w      = (const float*)d_in[19];
  const float* attW_b      = (const float*)d_in[20];
  const float* fc_w        = (const float*)d_in[21];
  const float* fc_b        = (const float*)d_in[22];
  const float* ln_g        = (const float*)d_in[23];
  const float* ln_b        = (const float*)d_in[24];
  const float* cls_mlp_w   = (const float*)d_in[25];
  const float* cls_mlp_b   = (const float*)d_in[26];
  const float* reg_mlp_w   = (const float*)d_in[27];
  const float* reg_mlp_b   = (const float*)d_in[28];
  const float* cls_head_w  = (const float*)d_in[29];
  const float* cls_head_b  = (const float*)d_in[30];
  const float* reg_head_w  = (const float*)d_in[31];
  const float* reg_head_b  = (const float*)d_in[32];
  float* out = (float*)d_out;

  char* wp = (char*)d_ws;
  auto alloc = [&](size_t bytes) { char* r = wp; wp += (bytes + 255) & ~(size_t)255; return r; };

  float* priA   = (float*)alloc((size_t)BB * PP * 78 * 4);
  float* priB   = (float*)alloc((size_t)BB * PP * 78 * 4);
  float* roi_fc = (float*)alloc((size_t)BB * PP * 64 * 4);
  float* keyb   = (float*)alloc((size_t)BB * 64 * 250 * 4);
  float* valb   = (float*)alloc((size_t)BB * 64 * 250 * 4);
  unsigned short* Wr   = (unsigned short*)alloc(82944ull * 2);
  unsigned short* Wc   = (unsigned short*)alloc(221184ull * 2);
  unsigned short* fw   = (unsigned short*)alloc(147456ull * 2);
  unsigned short* cfg  = (unsigned short*)alloc(3ull * 12288 * 36 * 48 * 2);
  unsigned short* catf = (unsigned short*)alloc(12288ull * 36 * 64 * 2);
  unsigned short* fmT  = (unsigned short*)alloc((size_t)BB * 64 * 80 * 64 * 2); // stage-0 size, reused

  const int HW[3][2] = {{64, 80}, {32, 40}, {16, 20}};
  const size_t wcoff[3] = {0, 36864, 110592};

  k_init_priors<<<dim3((BB * PP * 78 + 255) / 256), dim3(256), 0, stream>>>(priors, priA);
  k_repack<<<dim3((451584 + 255) / 256), dim3(256), 0, stream>>>(
      convs_w, cat_w[0], cat_w[1], cat_w[2], fc_w, Wr, Wc, fw);

  float* pcur = priA;
  float* pnext = priB;
  for (int s = 0; s < 3; ++s) {
    int H = HW[s][0], W = HW[s][1];
    int hw = H * W;
    int tiles = hw / 64;
    k_transpose<<<dim3(BB * tiles), dim3(256), 0, stream>>>(feat[s], hw, tiles, fmT);

    k_keyval<<<dim3(BB * 250), dim3(64), 0, stream>>>(
        fmT, H, W, fkey_w, fkey_scale, fkey_shift, fval_w, fval_b, keyb, valb);

    if (s == 0) {
      k_gatherconv<0><<<dim3(1536), dim3(256), 0, stream>>>(
          fmT, pcur, Wr + 0 * 27648, convs_scale + 0, convs_shift + 0,
          cfg + 0ull * 12288 * 36 * 48);
      k_cat<0><<<dim3(1536), dim3(256), 0, stream>>>(
          cfg, Wc + wcoff[0], cat_scale + 0, cat_shift + 0, catf);
    } else if (s == 1) {
      k_gatherconv<1><<<dim3(1536), dim3(256), 0, stream>>>(
          fmT, pcur, Wr + 1 * 27648, convs_scale + 48, convs_shift + 48,
          cfg + 1ull * 12288 * 36 * 48);
      k_cat<1><<<dim3(1536), dim3(256), 0, stream>>>(
          cfg, Wc + wcoff[1], cat_scale + 64, cat_shift + 64, catf);
    } else {
      k_gatherconv<2><<<dim3(1536), dim3(256), 0, stream>>>(
          fmT, pcur, Wr + 2 * 27648, convs_scale + 96, convs_shift + 96,
          cfg + 2ull * 12288 * 36 * 48);
      k_cat<2><<<dim3(1536), dim3(256), 0, stream>>>(
          cfg, Wc + wcoff[2], cat_scale + 128, cat_shift + 128, catf);
    }

    k_fc<<<dim3(192), dim3(256), 0, stream>>>(catf, fw, fc_b, ln_g, ln_b, roi_fc);

    k_att<<<dim3(BB * PP), dim3(256), 0, stream>>>(
        roi_fc, keyb, valb, fq_w, fq_b, attW_w, attW_b,
        cls_mlp_w, cls_mlp_b, reg_mlp_w, reg_mlp_b,
        cls_head_w, cls_head_b, reg_head_w, reg_head_b,
        pcur, (s < 2) ? pnext : (float*)nullptr,
        out + (size_t)s * BB * PP * 78);

    float* tmp = pcur; pcur = pnext; pnext = tmp;
  }
}

// Round 4
// 1151.068 us; speedup vs baseline: 7.6041x; 1.7597x over previous
//
#include <hip/hip_runtime.h>
#include <hip/hip_bf16.h>

#define BB 64
#define PP 192
#define SS 36
#define PI_F 3.14159265358979323846f

typedef __attribute__((ext_vector_type(8))) __bf16 bf16x8;
typedef __attribute__((ext_vector_type(4))) float f32x4;
typedef __attribute__((ext_vector_type(8))) unsigned short us8;

__device__ inline unsigned short f2bf(float f) {
  unsigned int u = __builtin_bit_cast(unsigned int, f);
  unsigned int r = (u + 0x7FFFu + ((u >> 16) & 1u)) >> 16;
  return (unsigned short)r;
}

__device__ inline float bf2f(unsigned short u) {
  return __builtin_bit_cast(float, (unsigned int)u << 16);
}

__device__ inline bf16x8 ld8(const unsigned short* p) {
  us8 v = *(const us8*)p;
  return __builtin_bit_cast(bf16x8, v);
}

// ---------------------------------------------------------------------------
// K0: broadcast priors (P,78) -> (B,P,78)
// ---------------------------------------------------------------------------
__global__ __launch_bounds__(256)
void k_init_priors(const float* __restrict__ priors, float* __restrict__ out) {
  int idx = blockIdx.x * 256 + threadIdx.x;
  if (idx < BB * PP * 78) out[idx] = priors[idx % (PP * 78)];
}

// ---------------------------------------------------------------------------
// K0b: fmap [B][C][H][W] fp32 -> fmT [B][H*W][C] bf16 (pixel-major).
// ---------------------------------------------------------------------------
__global__ __launch_bounds__(256)
void k_transpose(const float* __restrict__ fmap, int HW, int tiles_per_b,
                 unsigned short* __restrict__ fmT) {
  __shared__ unsigned short Ls[64][66];
  int b = blockIdx.x / tiles_per_b;
  int p0 = (blockIdx.x % tiles_per_b) * 64;
  int tid = threadIdx.x;
  for (int idx = tid; idx < 4096; idx += 256) {
    int c = idx >> 6, pos = idx & 63;
    Ls[c][pos] = f2bf(fmap[((size_t)b * 64 + c) * HW + p0 + pos]);
  }
  __syncthreads();
  for (int idx = tid; idx < 4096; idx += 256) {
    int pos = idx >> 6, c = idx & 63;
    fmT[((size_t)b * HW + p0 + pos) * 64 + c] = Ls[c][pos];
  }
}

// ---------------------------------------------------------------------------
// Repack weights to bf16 MFMA-A layouts.
// Sections: Wr[82944] | Wc[221184] | fw[147456] |
//           wm[22528] = w1c,w2c,w1r,w2r (4x4096), hc (16x64), hr (80x64)
// ---------------------------------------------------------------------------
__global__ __launch_bounds__(256)
void k_repack(const float* __restrict__ cw,
              const float* __restrict__ c0, const float* __restrict__ c1,
              const float* __restrict__ c2, const float* __restrict__ fcw,
              const float* __restrict__ clsW, const float* __restrict__ regW,
              const float* __restrict__ chw, const float* __restrict__ rhw,
              unsigned short* __restrict__ Wr, unsigned short* __restrict__ Wc,
              unsigned short* __restrict__ fw, unsigned short* __restrict__ wm) {
  int idx = blockIdx.x * 256 + threadIdx.x;
  if (idx < 82944) {
    int c = idx & 63; int t = idx >> 6; int o = t % 48; t /= 48;
    int k = t % 9; int s = t / 9;
    Wr[idx] = f2bf(cw[((size_t)(s * 48 + o) * 64 + c) * 9 + k]);
  } else if (idx < 82944 + 221184) {
    int r = idx - 82944;
    int s, base, NC;
    if (r < 36864)            { s = 0; base = 0;      NC = 1; }
    else if (r < 110592)      { s = 1; base = 36864;  NC = 2; }
    else                      { s = 2; base = 110592; NC = 3; }
    int q = r - base;
    int c = q & 63; int t = q >> 6; int o = t & 63; t >>= 6;
    int k = t % 9; int i = t / 9;
    const float* src = (s == 0) ? c0 : (s == 1) ? c1 : c2;
    float v = (c < 48) ? src[((size_t)o * (NC * 48) + i * 48 + c) * 9 + k] : 0.f;
    Wc[r] = f2bf(v);
  } else if (idx < 82944 + 221184 + 147456) {
    int q = idx - (82944 + 221184);
    int h = q / 2304; int kp = q % 2304; int j = kp >> 6; int c = kp & 63;
    fw[q] = f2bf(fcw[(size_t)h * 2304 + c * 36 + j]);
  } else if (idx < 82944 + 221184 + 147456 + 22528) {
    int q = idx - (82944 + 221184 + 147456);
    unsigned short v;
    if (q < 4096)        v = f2bf(clsW[q]);
    else if (q < 8192)   v = f2bf(clsW[4096 + (q - 4096)]);
    else if (q < 12288)  v = f2bf(regW[q - 8192]);
    else if (q < 16384)  v = f2bf(regW[4096 + (q - 12288)]);
    else if (q < 17408) { int r = q - 16384; int o = r >> 6, c = r & 63;
                          v = (o < 2) ? f2bf(chw[o * 64 + c]) : (unsigned short)0; }
    else                { int r = q - 17408; int o = r >> 6, c = r & 63;
                          v = (o < 76) ? f2bf(rhw[o * 64 + c]) : (unsigned short)0; }
    wm[q] = v;
  }
}

// ---------------------------------------------------------------------------
// K2: key/value in MFMA-B layouts. Block = (b, 64-key tile); 256 blocks.
// keyT [b][key(256 pad)][c64] bf16 ; valB [b][c64][key(256 pad)] bf16.
// Pad keys >= 250 get finite garbage (masked in QK) / bias values (sim=0).
// ---------------------------------------------------------------------------
__global__ __launch_bounds__(256)
void k_kv(const unsigned short* __restrict__ fmT, int H, int W,
          const float* __restrict__ fkey_w, const float* __restrict__ fkey_scale,
          const float* __restrict__ fkey_shift,
          const float* __restrict__ fval_w, const float* __restrict__ fval_b,
          unsigned short* __restrict__ keyT, unsigned short* __restrict__ valB) {
  __shared__ float pix[64][68];
  __shared__ __align__(16) unsigned short kout[64][80];   // [key][o]
  __shared__ __align__(16) unsigned short vout[64][80];   // [c][key]
  int tid = threadIdx.x;
  int b = blockIdx.x >> 2;
  int k0 = (blockIdx.x & 3) * 64;

  {
    int key = tid >> 2, cq = tid & 3;
    int k = k0 + key;
    float v[16];
    if (k < 250) {
      int r = k / 25, c2 = k % 25;
      int iy = (r * H) / 10, ix = (c2 * W) / 25;
      const unsigned short* src = fmT + ((size_t)b * H * W + iy * W + ix) * 64 + cq * 16;
      us8 a = *(const us8*)src;
      us8 bb = *(const us8*)(src + 8);
#pragma unroll
      for (int e = 0; e < 8; ++e) { v[e] = bf2f(a[e]); v[8 + e] = bf2f(bb[e]); }
    } else {
#pragma unroll
      for (int e = 0; e < 16; ++e) v[e] = 0.f;
    }
#pragma unroll
    for (int e = 0; e < 16; ++e) pix[key][cq * 16 + e] = v[e];
  }
  __syncthreads();

  {
    int o = tid >> 2, kq = tid & 3;
    float ak[16], av[16];
#pragma unroll
    for (int kk = 0; kk < 16; ++kk) { ak[kk] = 0.f; av[kk] = 0.f; }
    for (int c = 0; c < 64; ++c) {
      float wk = fkey_w[o * 64 + c], wvv = fval_w[o * 64 + c];
#pragma unroll
      for (int kk = 0; kk < 16; ++kk) {
        float pv = pix[kq * 16 + kk][c];
        ak[kk] += pv * wk; av[kk] += pv * wvv;
      }
    }
    float sc_ = fkey_scale[o], sh = fkey_shift[o], vb_ = fval_b[o];
#pragma unroll
    for (int kk = 0; kk < 16; ++kk) {
      int k = kq * 16 + kk;
      float kf = ak[kk] * sc_ + sh; kf = kf > 0.f ? kf : 0.f;
      kout[k][o] = f2bf(kf);
      vout[o][k] = f2bf(av[kk] + vb_);
    }
  }
  __syncthreads();

  {
    int row = tid >> 2, oq = tid & 3;
    *(us8*)(keyT + ((size_t)b * 256 + k0 + row) * 64 + oq * 16)     = *(us8*)&kout[row][oq * 16];
    *(us8*)(keyT + ((size_t)b * 256 + k0 + row) * 64 + oq * 16 + 8) = *(us8*)&kout[row][oq * 16 + 8];
    *(us8*)(valB + ((size_t)b * 64 + row) * 256 + k0 + oq * 16)     = *(us8*)&vout[row][oq * 16];
    *(us8*)(valB + ((size_t)b * 64 + row) * 256 + k0 + oq * 16 + 8) = *(us8*)&vout[row][oq * 16 + 8];
  }
}

// ---------------------------------------------------------------------------
// K1a: fused gather + conv_s (MFMA).
// ---------------------------------------------------------------------------
template <int STAGE>
__global__ __launch_bounds__(256)
void k_gatherconv(const unsigned short* __restrict__ fmT,
                  const float* __restrict__ priors_cur,
                  const unsigned short* __restrict__ Wr,
                  const float* __restrict__ cscale, const float* __restrict__ cshift,
                  unsigned short* __restrict__ cfg) {
  constexpr int H = (STAGE == 0) ? 64 : (STAGE == 1) ? 32 : 16;
  constexpr int W = (STAGE == 0) ? 80 : (STAGE == 1) ? 40 : 20;
  constexpr int HW = H * W;

  __shared__ float posx[8][36], posy[8][36];
  __shared__ __align__(16) unsigned short Xs[360][64];

  int tid = threadIdx.x;
  int r0 = blockIdx.x * 8;

  for (int idx = tid; idx < 288; idx += 256) {
    int q = idx / 36, j = idx % 36;
    int bp = r0 + q;
    int k = 35 - j;
    int sx = (int)(((float)k / 35.0f) * 71.0f);
    float px = priors_cur[(size_t)bp * 78 + 6 + sx];
    posx[q][j] = px * (float)(W - 1);
    float fy = 1.0f - (float)sx / 71.0f;
    posy[q][j] = fy * (float)(H - 1);
  }
  __syncthreads();

  for (int idx = tid; idx < 360 * 8; idx += 256) {
    int row = idx >> 3, ch8 = idx & 7;
    int p = row - 4;
    unsigned short pk[8] = {0, 0, 0, 0, 0, 0, 0, 0};
    if (p >= 0 && p < 352) {
      int q = p / 44, x = p % 44;
      if (x >= 4 && x < 40) {
        int j = x - 4;
        int b = (r0 + q) / PP;
        float fx = posx[q][j];
        float fy = posy[q][j];
        float x0 = floorf(fx), y0 = floorf(fy);
        float wx = fx - x0, wy = fy - y0;
        float xs2[2] = {x0, x0 + 1.f};
        float ys2[2] = {y0, y0 + 1.f};
        float wxs[2] = {1.f - wx, wx};
        float wys[2] = {1.f - wy, wy};
        float accf[8] = {0.f, 0.f, 0.f, 0.f, 0.f, 0.f, 0.f, 0.f};
#pragma unroll
        for (int ty = 0; ty < 2; ++ty)
#pragma unroll
          for (int tx = 0; tx < 2; ++tx) {
            float xf = xs2[tx], yf = ys2[ty];
            bool v = (xf >= 0.f) && (xf <= (float)(W - 1)) &&
                     (yf >= 0.f) && (yf <= (float)(H - 1));
            int xi = (int)fminf(fmaxf(xf, 0.f), (float)(W - 1));
            int yi = (int)fminf(fmaxf(yf, 0.f), (float)(H - 1));
            float wgt = v ? (wxs[tx] * wys[ty]) : 0.f;
            const us8 vv = *(const us8*)(fmT + ((size_t)b * HW + yi * W + xi) * 64 + ch8 * 8);
#pragma unroll
            for (int e = 0; e < 8; ++e) accf[e] += wgt * bf2f(vv[e]);
          }
#pragma unroll
        for (int e = 0; e < 8; ++e) pk[e] = f2bf(accf[e]);
      }
    }
    int pc = ch8 ^ (row & 7);
    *(us8*)&Xs[row][pc * 8] = *(us8*)pk;
  }
  __syncthreads();

  int wv = tid >> 6, lane = tid & 63, l15 = lane & 15, quad = lane >> 4;
  f32x4 acc[3][6];
#pragma unroll
  for (int m = 0; m < 3; ++m)
#pragma unroll
    for (int s = 0; s < 6; ++s) acc[m][s] = (f32x4)0.f;

  for (int k = 0; k < 9; ++k) {
#pragma unroll
    for (int kk = 0; kk < 2; ++kk) {
      bf16x8 af[3];
#pragma unroll
      for (int m = 0; m < 3; ++m)
        af[m] = ld8(Wr + ((size_t)(k * 48 + m * 16 + l15)) * 64 + kk * 32 + quad * 8);
#pragma unroll
      for (int s = 0; s < 6; ++s) {
        int nt = wv + 4 * s;
        if (nt < 22) {
          int row = nt * 16 + l15 + k;
          int pc = (kk * 4 + quad) ^ (row & 7);
          bf16x8 bfr = ld8(&Xs[row][pc * 8]);
#pragma unroll
          for (int m = 0; m < 3; ++m)
            acc[m][s] = __builtin_amdgcn_mfma_f32_16x16x32_bf16(af[m], bfr, acc[m][s], 0, 0, 0);
        }
      }
    }
  }

#pragma unroll
  for (int s = 0; s < 6; ++s) {
    int nt = wv + 4 * s;
    if (nt < 22) {
      int p = nt * 16 + l15;
      int q = p / 44, x = p % 44;
      if (x >= 4 && x < 40) {
        int bp = r0 + q;
#pragma unroll
        for (int m = 0; m < 3; ++m) {
          int o0 = m * 16 + quad * 4;
          unsigned short pk[4];
#pragma unroll
          for (int rg = 0; rg < 4; ++rg) {
            float v = acc[m][s][rg] * cscale[o0 + rg] + cshift[o0 + rg];
            pk[rg] = f2bf(v > 0.f ? v : 0.f);
          }
          *(uint2*)(cfg + ((size_t)bp * 36 + (x - 4)) * 48 + o0) = *(uint2*)pk;
        }
      }
    }
  }
}

// ---------------------------------------------------------------------------
// K1b: cat conv (MFMA).
// ---------------------------------------------------------------------------
template <int STAGE>
__global__ __launch_bounds__(256)
void k_cat(const unsigned short* __restrict__ cfg_all,
           const unsigned short* __restrict__ Wc,
           const float* __restrict__ kscale, const float* __restrict__ kshift,
           unsigned short* __restrict__ catf) {
  constexpr int NC = STAGE + 1;
  __shared__ __align__(16) unsigned short cfs[360][64];
  int tid = threadIdx.x;
  int r0 = blockIdx.x * 8;
  int wv = tid >> 6, lane = tid & 63, l15 = lane & 15, quad = lane >> 4;

  f32x4 acc[4][6];
#pragma unroll
  for (int m = 0; m < 4; ++m)
#pragma unroll
    for (int s = 0; s < 6; ++s) acc[m][s] = (f32x4)0.f;

#pragma unroll
  for (int i = 0; i < NC; ++i) {
    __syncthreads();
    for (int idx = tid; idx < 360 * 8; idx += 256) {
      int row = idx >> 3, ch = idx & 7;
      int p = row - 4;
      us8 v = (us8)(unsigned short)0;
      if (p >= 0 && p < 352 && ch < 6) {
        int q = p / 44, x = p % 44;
        if (x >= 4 && x < 40) {
          const unsigned short* src = cfg_all + (size_t)i * (12288ull * 36 * 48) +
                                      ((size_t)(r0 + q) * 36 + (x - 4)) * 48 + ch * 8;
          v = *(const us8*)src;
        }
      }
      int pc = ch ^ (row & 7);
      *(us8*)&cfs[row][pc * 8] = v;
    }
    __syncthreads();

    for (int k = 0; k < 9; ++k) {
#pragma unroll
      for (int kk = 0; kk < 2; ++kk) {
        bf16x8 af[4];
#pragma unroll
        for (int m = 0; m < 4; ++m)
          af[m] = ld8(Wc + (((size_t)i * 9 + k) * 64 + m * 16 + l15) * 64 + kk * 32 + quad * 8);
#pragma unroll
        for (int s = 0; s < 6; ++s) {
          int nt = wv + 4 * s;
          if (nt < 22) {
            int row = nt * 16 + l15 + k;
            int pc = (kk * 4 + quad) ^ (row & 7);
            bf16x8 bfr = ld8(&cfs[row][pc * 8]);
#pragma unroll
            for (int m = 0; m < 4; ++m)
              acc[m][s] = __builtin_amdgcn_mfma_f32_16x16x32_bf16(af[m], bfr, acc[m][s], 0, 0, 0);
          }
        }
      }
    }
  }

#pragma unroll
  for (int s = 0; s < 6; ++s) {
    int nt = wv + 4 * s;
    if (nt < 22) {
      int p = nt * 16 + l15;
      int q = p / 44, x = p % 44;
      if (x >= 4 && x < 40) {
        int bp = r0 + q;
#pragma unroll
        for (int m = 0; m < 4; ++m) {
          int o0 = m * 16 + quad * 4;
          unsigned short pk[4];
#pragma unroll
          for (int rg = 0; rg < 4; ++rg) {
            float v = acc[m][s][rg] * kscale[o0 + rg] + kshift[o0 + rg];
            pk[rg] = f2bf(v > 0.f ? v : 0.f);
          }
          *(uint2*)(catf + ((size_t)bp * 36 + (x - 4)) * 64 + o0) = *(uint2*)pk;
        }
      }
    }
  }
}

// ---------------------------------------------------------------------------
// K1c: fc GEMM + bias + LayerNorm + relu.
// ---------------------------------------------------------------------------
__global__ __launch_bounds__(256)
void k_fc(const unsigned short* __restrict__ catf,
          const unsigned short* __restrict__ fw,
          const float* __restrict__ fc_b,
          const float* __restrict__ ln_g, const float* __restrict__ ln_b,
          float* __restrict__ roi_fc) {
  __shared__ __align__(16) float fcb[64][68];
  int tid = threadIdx.x, wv = tid >> 6, lane = tid & 63, l15 = lane & 15, quad = lane >> 4;
  int nbase = blockIdx.x * 64 + wv * 16;

  f32x4 acc[4];
#pragma unroll
  for (int m = 0; m < 4; ++m) acc[m] = (f32x4)0.f;

  for (int ks = 0; ks < 72; ++ks) {
    int j = ks >> 1, ch = (ks & 1) * 32;
    bf16x8 bfr = ld8(catf + ((size_t)(nbase + l15) * 36 + j) * 64 + ch + quad * 8);
#pragma unroll
    for (int m = 0; m < 4; ++m) {
      bf16x8 af = ld8(fw + (size_t)(m * 16 + l15) * 2304 + ks * 32 + quad * 8);
      acc[m] = __builtin_amdgcn_mfma_f32_16x16x32_bf16(af, bfr, acc[m], 0, 0, 0);
    }
  }

#pragma unroll
  for (int m = 0; m < 4; ++m) {
    f32x4 v;
#pragma unroll
    for (int rg = 0; rg < 4; ++rg) v[rg] = acc[m][rg] + fc_b[m * 16 + quad * 4 + rg];
    *(f32x4*)&fcb[wv * 16 + l15][m * 16 + quad * 4] = v;
  }
  __syncthreads();

  for (int rr = 0; rr < 16; ++rr) {
    int rl = wv * 16 + rr;
    float y = fcb[rl][lane];
    float s = y;
#pragma unroll
    for (int off = 32; off > 0; off >>= 1) s += __shfl_xor(s, off, 64);
    float mu = s * (1.f / 64.f);
    float d = y - mu;
    float v2 = d * d;
#pragma unroll
    for (int off = 32; off > 0; off >>= 1) v2 += __shfl_xor(v2, off, 64);
    float var = v2 * (1.f / 64.f);
    float r = d / sqrtf(var + 1e-5f) * ln_g[lane] + ln_b[lane];
    roi_fc[(size_t)(blockIdx.x * 64 + rl) * 64 + lane] = r > 0.f ? r : 0.f;
  }
}

// ---------------------------------------------------------------------------
// helper: one 16(M)x16(N)x64(K) GEMM tile: A = W rows (global bf16),
// B = X from LDS wave region [16 rows][64 k], chunk-swizzled by (row&7).
// ---------------------------------------------------------------------------
__device__ inline f32x4 gemm_tile(const unsigned short* __restrict__ Wrow0,
                                  const unsigned short* Xl, int l15, int quad) {
  f32x4 a = (f32x4)0.f;
#pragma unroll
  for (int kk = 0; kk < 2; ++kk) {
    bf16x8 af = ld8(Wrow0 + (size_t)l15 * 64 + kk * 32 + quad * 8);
    bf16x8 bx = ld8(Xl + l15 * 64 + (((kk * 4 + quad) ^ (l15 & 7)) * 8));
    a = __builtin_amdgcn_mfma_f32_16x16x32_bf16(af, bx, a, 0, 0, 0);
  }
  return a;
}

// ---------------------------------------------------------------------------
// K3: batched attention + MLP heads + tan epilogue, all MFMA.
// Block = 64 rois (1/3 of a batch); grid = 192. One __syncthreads total.
// ---------------------------------------------------------------------------
__global__ __launch_bounds__(256)
void k_att2(const float* __restrict__ roi_fc,
            const unsigned short* __restrict__ keyT,   // [B][256][64]
            const unsigned short* __restrict__ valB,   // [B][64][256]
            const float* __restrict__ fq_w, const float* __restrict__ fq_b,
            const float* __restrict__ attW_w, const float* __restrict__ attW_b,
            const unsigned short* __restrict__ wm,
            const float* __restrict__ cls_mlp_b, const float* __restrict__ reg_mlp_b,
            const float* __restrict__ cls_head_b, const float* __restrict__ reg_head_b,
            const float* __restrict__ priors_cur,
            float* __restrict__ priors_next,
            float* __restrict__ preds) {
  __shared__ __align__(16) unsigned char smem[8192 + 4 * 4608 + 4 * 8192];
  unsigned short* qx = (unsigned short*)smem;                   // q / x union
  unsigned char* Bb = smem + 8192;                              // rf / hA,hB union
  unsigned char* Cb = smem + 8192 + 4 * 4608;                   // sim / rego union

  int tid = threadIdx.x, wv = tid >> 6, lane = tid & 63;
  int l15 = lane & 15, quad = lane >> 4;
  int rb = blockIdx.x * 64;
  int b = rb / PP;
  int p_base = rb % PP;

  float* rf = (float*)(Bb + wv * 4608);                         // [16][68] f32
  unsigned short* hA = (unsigned short*)(Bb + wv * 4608);       // [16][64] bf16
  unsigned short* hB = (unsigned short*)(Bb + wv * 4608 + 2304);
  unsigned short* simw = (unsigned short*)(Cb + wv * 8192);     // [16][256] bf16
  unsigned short* rego = (unsigned short*)(Cb + wv * 8192);     // [16][80] bf16
  unsigned short* clso = (unsigned short*)(Cb + wv * 8192 + 2560); // [16][2]

  // ---- phase 1: load roi_fc -> rf (f32) + q (bf16, swizzled) ----
  for (int it = tid; it < 512; it += 256) {
    int row = it >> 3, ch = it & 7;
    const float* src = roi_fc + (size_t)(rb + row) * 64 + ch * 8;
    float v[8];
#pragma unroll
    for (int e = 0; e < 8; ++e) v[e] = src[e];
    float* rfw = (float*)(Bb + (row >> 4) * 4608);
#pragma unroll
    for (int e = 0; e < 8; ++e) rfw[(row & 15) * 68 + ch * 8 + e] = v[e];
    int p = p_base + row;
    float qw = fq_w[p], qb = fq_b[p];
    unsigned short pk[8];
#pragma unroll
    for (int e = 0; e < 8; ++e) {
      float q = v[e] * qw + qb;
      pk[e] = f2bf(q > 0.f ? q : 0.f);
    }
    *(us8*)&qx[row * 64 + ((ch ^ (row & 7)) * 8)] = *(us8*)pk;
  }
  __syncthreads();

  // ---- phase 2: QK^T (M=16 wave rois, N=256 keys, K=64) + softmax ----
  f32x4 sc[16];
#pragma unroll
  for (int nt = 0; nt < 16; ++nt) sc[nt] = (f32x4)0.f;
  const unsigned short* kb = keyT + (size_t)b * 256 * 64;
#pragma unroll
  for (int kk = 0; kk < 2; ++kk) {
    bf16x8 af = ld8(&qx[(wv * 16 + l15) * 64 + (((kk * 4 + quad) ^ (l15 & 7)) * 8)]);
#pragma unroll
    for (int nt = 0; nt < 16; ++nt) {
      bf16x8 bf_ = ld8(kb + (size_t)(nt * 16 + l15) * 64 + kk * 32 + quad * 8);
      sc[nt] = __builtin_amdgcn_mfma_f32_16x16x32_bf16(af, bf_, sc[nt], 0, 0, 0);
    }
  }
  float mx[4] = {-1e30f, -1e30f, -1e30f, -1e30f};
#pragma unroll
  for (int nt = 0; nt < 16; ++nt)
#pragma unroll
    for (int rg = 0; rg < 4; ++rg) {
      float s = sc[nt][rg] * 0.125f;
      if (nt == 15 && l15 >= 10) s = -1e30f;     // keys >= 250
      sc[nt][rg] = s;
      mx[rg] = fmaxf(mx[rg], s);
    }
#pragma unroll
  for (int rg = 0; rg < 4; ++rg)
#pragma unroll
    for (int off = 1; off < 16; off <<= 1)
      mx[rg] = fmaxf(mx[rg], __shfl_xor(mx[rg], off, 64));
  float sm[4] = {0.f, 0.f, 0.f, 0.f};
#pragma unroll
  for (int nt = 0; nt < 16; ++nt)
#pragma unroll
    for (int rg = 0; rg < 4; ++rg) {
      float e = expf(sc[nt][rg] - mx[rg]);
      sc[nt][rg] = e;
      sm[rg] += e;
    }
#pragma unroll
  for (int rg = 0; rg < 4; ++rg)
#pragma unroll
    for (int off = 1; off < 16; off <<= 1)
      sm[rg] += __shfl_xor(sm[rg], off, 64);
  float rs[4];
#pragma unroll
  for (int rg = 0; rg < 4; ++rg) rs[rg] = 1.f / sm[rg];
  // write sim in A-layout (row = quad*4+rg, col = nt*16+l15), swizzled
#pragma unroll
  for (int nt = 0; nt < 16; ++nt)
#pragma unroll
    for (int rg = 0; rg < 4; ++rg) {
      int row = quad * 4 + rg, col = nt * 16 + l15;
      simw[row * 256 + (((col >> 3) ^ (row & 7)) * 8) + (col & 7)] = f2bf(sc[nt][rg] * rs[rg]);
    }

  // ---- phase 3: PV (M=16 rois, N=64 c, K=256) + residual + attW ----
  f32x4 cv[4];
#pragma unroll
  for (int nt = 0; nt < 4; ++nt) cv[nt] = (f32x4)0.f;
  const unsigned short* vb = valB + (size_t)b * 64 * 256;
#pragma unroll
  for (int ks = 0; ks < 8; ++ks) {
    bf16x8 af = ld8(&simw[l15 * 256 + (((ks * 4 + quad) ^ (l15 & 7)) * 8)]);
#pragma unroll
    for (int nt = 0; nt < 4; ++nt) {
      bf16x8 bf_ = ld8(vb + (size_t)(nt * 16 + l15) * 256 + ks * 32 + quad * 8);
      cv[nt] = __builtin_amdgcn_mfma_f32_16x16x32_bf16(af, bf_, cv[nt], 0, 0, 0);
    }
  }
#pragma unroll
  for (int rg = 0; rg < 4; ++rg) {
    int row = quad * 4 + rg;
    int p = p_base + wv * 16 + row;
    float aw = attW_w[p], ab = attW_b[p];
#pragma unroll
    for (int nt = 0; nt < 4; ++nt) {
      int c = nt * 16 + l15;
      float xv = rf[row * 68 + c] + cv[nt][rg] * aw + ab;
      qx[(wv * 16 + row) * 64 + (((c >> 3) ^ (row & 7)) * 8) + (c & 7)] = f2bf(xv);
    }
  }

  // ---- phase 4: MLP chains (wave-local) ----
  const unsigned short* xw = qx + wv * 16 * 64;
  // cls path
#pragma unroll
  for (int mt = 0; mt < 4; ++mt) {
    f32x4 a = gemm_tile(wm + 0 + mt * 1024, xw, l15, quad);
#pragma unroll
    for (int rg = 0; rg < 4; ++rg) {
      int o = mt * 16 + quad * 4 + rg;
      float v = a[rg] + cls_mlp_b[o]; v = v > 0.f ? v : 0.f;
      hA[l15 * 64 + (((o >> 3) ^ (l15 & 7)) * 8) + (o & 7)] = f2bf(v);
    }
  }
#pragma unroll
  for (int mt = 0; mt < 4; ++mt) {
    f32x4 a = gemm_tile(wm + 4096 + mt * 1024, hA, l15, quad);
#pragma unroll
    for (int rg = 0; rg < 4; ++rg) {
      int o = mt * 16 + quad * 4 + rg;
      float v = a[rg] + cls_mlp_b[64 + o]; v = v > 0.f ? v : 0.f;
      hB[l15 * 64 + (((o >> 3) ^ (l15 & 7)) * 8) + (o & 7)] = f2bf(v);
    }
  }
  {
    f32x4 a = gemm_tile(wm + 16384, hB, l15, quad);
#pragma unroll
    for (int rg = 0; rg < 4; ++rg) {
      int o = quad * 4 + rg;
      if (o < 2) clso[l15 * 2 + o] = f2bf(a[rg] + cls_head_b[o]);
    }
  }
  // reg path
#pragma unroll
  for (int mt = 0; mt < 4; ++mt) {
    f32x4 a = gemm_tile(wm + 8192 + mt * 1024, xw, l15, quad);
#pragma unroll
    for (int rg = 0; rg < 4; ++rg) {
      int o = mt * 16 + quad * 4 + rg;
      float v = a[rg] + reg_mlp_b[o]; v = v > 0.f ? v : 0.f;
      hA[l15 * 64 + (((o >> 3) ^ (l15 & 7)) * 8) + (o & 7)] = f2bf(v);
    }
  }
#pragma unroll
  for (int mt = 0; mt < 4; ++mt) {
    f32x4 a = gemm_tile(wm + 12288 + mt * 1024, hA, l15, quad);
#pragma unroll
    for (int rg = 0; rg < 4; ++rg) {
      int o = mt * 16 + quad * 4 + rg;
      float v = a[rg] + reg_mlp_b[64 + o]; v = v > 0.f ? v : 0.f;
      hB[l15 * 64 + (((o >> 3) ^ (l15 & 7)) * 8) + (o & 7)] = f2bf(v);
    }
  }
#pragma unroll
  for (int mt = 0; mt < 5; ++mt) {
    f32x4 a = gemm_tile(wm + 17408 + mt * 1024, hB, l15, quad);
#pragma unroll
    for (int rg = 0; rg < 4; ++rg) {
      int o = mt * 16 + quad * 4 + rg;
      if (o < 76) rego[l15 * 80 + o] = f2bf(a[rg] + reg_head_b[o]);
    }
  }

  // ---- phase 5: epilogue (wave-local; 4 lanes per roi) ----
  {
    int p_local = lane >> 2, g = lane & 3;
    int bp = rb + wv * 16 + p_local;
    const float* pc = priors_cur + (size_t)bp * 78;
    float r0v = bf2f(rego[p_local * 80 + 0]);
    float r1v = bf2f(rego[p_local * 80 + 1]);
    float r2v = bf2f(rego[p_local * 80 + 2]);
    float r3v = bf2f(rego[p_local * 80 + 3]);
    float p0 = pc[2] + r0v;
    float p1 = pc[3] + r1v;
    float p2 = pc[4] + r2v;
    float* po = preds + (size_t)bp * 78;
    float* pn = priors_next ? priors_next + (size_t)bp * 78 : nullptr;
    if (g == 0) {
      float c0v = bf2f(clso[p_local * 2 + 0]);
      float c1v = bf2f(clso[p_local * 2 + 1]);
      po[0] = c0v; po[1] = c1v;
      po[2] = p0; po[3] = p1; po[4] = p2; po[5] = r3v;
      if (pn) { pn[0] = c0v; pn[1] = c1v; pn[2] = p0; pn[3] = p1; pn[4] = p2; pn[5] = r3v; }
    }
    float t = tanf(p2 * PI_F + 1e-5f);
    float inv_t = 512.f / t;
#pragma unroll 2
    for (int i = g * 18; i < g * 18 + 18; ++i) {
      float py = 1.0f - (float)i / 71.0f;
      float offs = (p1 * 639.0f + (1.0f - py - p0) * inv_t) * (1.0f / 639.0f);
      po[6 + i] = offs + bf2f(rego[p_local * 80 + 4 + i]);
      if (pn) pn[6 + i] = offs;
    }
  }
}

// ---------------------------------------------------------------------------
extern "C" void kernel_launch(void* const* d_in, const int* in_sizes, int n_in,
                              void* d_out, int out_size, void* d_ws, size_t ws_size,
                              hipStream_t stream) {
  (void)in_sizes; (void)n_in; (void)out_size; (void)ws_size;
  const float* feat[3] = {(const float*)d_in[0], (const float*)d_in[1], (const float*)d_in[2]};
  const float* priors      = (const float*)d_in[3];
  const float* convs_w     = (const float*)d_in[4];
  const float* convs_scale = (const float*)d_in[5];
  const float* convs_shift = (const float*)d_in[6];
  const float* cat_w[3]    = {(const float*)d_in[7], (const float*)d_in[8], (const float*)d_in[9]};
  const float* cat_scale   = (const float*)d_in[10];
  const float* cat_shift   = (const float*)d_in[11];
  const float* fkey_w      = (const float*)d_in[12];
  const float* fkey_scale  = (const float*)d_in[13];
  const float* fkey_shift  = (const float*)d_in[14];
  const float* fval_w      = (const float*)d_in[15];
  const float* fval_b      = (const float*)d_in[16];
  const float* fq_w        = (const float*)d_in[17];
  const float* fq_b        = (const float*)d_in[18];
  const float* attW_w      = (const float*)d_in[19];
  const float* attW_b      = (const float*)d_in[20];
  const float* fc_w        = (const float*)d_in[21];
  const float* fc_b        = (const float*)d_in[22];
  const float* ln_g        = (const float*)d_in[23];
  const float* ln_b        = (const float*)d_in[24];
  const float* cls_mlp_w   = (const float*)d_in[25];
  const float* cls_mlp_b   = (const float*)d_in[26];
  const float* reg_mlp_w   = (const float*)d_in[27];
  const float* reg_mlp_b   = (const float*)d_in[28];
  const float* cls_head_w  = (const float*)d_in[29];
  const float* cls_head_b  = (const float*)d_in[30];
  const float* reg_head_w  = (const float*)d_in[31];
  const float* reg_head_b  = (const float*)d_in[32];
  float* out = (float*)d_out;

  char* wp = (char*)d_ws;
  auto alloc = [&](size_t bytes) { char* r = wp; wp += (bytes + 255) & ~(size_t)255; return r; };

  float* priA   = (float*)alloc((size_t)BB * PP * 78 * 4);
  float* priB   = (float*)alloc((size_t)BB * PP * 78 * 4);
  float* roi_fc = (float*)alloc((size_t)BB * PP * 64 * 4);
  unsigned short* keyT = (unsigned short*)alloc((size_t)BB * 256 * 64 * 2);
  unsigned short* valB = (unsigned short*)alloc((size_t)BB * 64 * 256 * 2);
  unsigned short* Wr   = (unsigned short*)alloc(82944ull * 2);
  unsigned short* Wc   = (unsigned short*)alloc(221184ull * 2);
  unsigned short* fw   = (unsigned short*)alloc(147456ull * 2);
  unsigned short* wm   = (unsigned short*)alloc(22528ull * 2);
  unsigned short* cfg  = (unsigned short*)alloc(3ull * 12288 * 36 * 48 * 2);
  unsigned short* catf = (unsigned short*)alloc(12288ull * 36 * 64 * 2);
  unsigned short* fmT  = (unsigned short*)alloc((size_t)BB * 64 * 80 * 64 * 2);

  const int HW[3][2] = {{64, 80}, {32, 40}, {16, 20}};
  const size_t wcoff[3] = {0, 36864, 110592};

  k_init_priors<<<dim3((BB * PP * 78 + 255) / 256), dim3(256), 0, stream>>>(priors, priA);
  k_repack<<<dim3((474112 + 255) / 256), dim3(256), 0, stream>>>(
      convs_w, cat_w[0], cat_w[1], cat_w[2], fc_w,
      cls_mlp_w, reg_mlp_w, cls_head_w, reg_head_w, Wr, Wc, fw, wm);

  float* pcur = priA;
  float* pnext = priB;
  for (int s = 0; s < 3; ++s) {
    int H = HW[s][0], W = HW[s][1];
    int hw = H * W;
    int tiles = hw / 64;
    k_transpose<<<dim3(BB * tiles), dim3(256), 0, stream>>>(feat[s], hw, tiles, fmT);

    k_kv<<<dim3(BB * 4), dim3(256), 0, stream>>>(
        fmT, H, W, fkey_w, fkey_scale, fkey_shift, fval_w, fval_b, keyT, valB);

    if (s == 0) {
      k_gatherconv<0><<<dim3(1536), dim3(256), 0, stream>>>(
          fmT, pcur, Wr + 0 * 27648, convs_scale + 0, convs_shift + 0,
          cfg + 0ull * 12288 * 36 * 48);
      k_cat<0><<<dim3(1536), dim3(256), 0, stream>>>(
          cfg, Wc + wcoff[0], cat_scale + 0, cat_shift + 0, catf);
    } else if (s == 1) {
      k_gatherconv<1><<<dim3(1536), dim3(256), 0, stream>>>(
          fmT, pcur, Wr + 1 * 27648, convs_scale + 48, convs_shift + 48,
          cfg + 1ull * 12288 * 36 * 48);
      k_cat<1><<<dim3(1536), dim3(256), 0, stream>>>(
          cfg, Wc + wcoff[1], cat_scale + 64, cat_shift + 64, catf);
    } else {
      k_gatherconv<2><<<dim3(1536), dim3(256), 0, stream>>>(
          fmT, pcur, Wr + 2 * 27648, convs_scale + 96, convs_shift + 96,
          cfg + 2ull * 12288 * 36 * 48);
      k_cat<2><<<dim3(1536), dim3(256), 0, stream>>>(
          cfg, Wc + wcoff[2], cat_scale + 128, cat_shift + 128, catf);
    }

    k_fc<<<dim3(192), dim3(256), 0, stream>>>(catf, fw, fc_b, ln_g, ln_b, roi_fc);

    k_att2<<<dim3(192), dim3(256), 0, stream>>>(
        roi_fc, keyT, valB, fq_w, fq_b, attW_w, attW_b, wm,
        cls_mlp_b, reg_mlp_b, cls_head_b, reg_head_b,
        pcur, (s < 2) ? pnext : (float*)nullptr,
        out + (size_t)s * BB * PP * 78);

    float* tmp = pcur; pcur = pnext; pnext = tmp;
  }
}

// Round 5
// 1032.426 us; speedup vs baseline: 8.4779x; 1.1149x over previous
//
#include <hip/hip_runtime.h>
#include <hip/hip_bf16.h>

#define BB 64
#define PP 192
#define SS 36
#define PI_F 3.14159265358979323846f

typedef __attribute__((ext_vector_type(8))) __bf16 bf16x8;
typedef __attribute__((ext_vector_type(4))) float f32x4;
typedef __attribute__((ext_vector_type(16))) float f32x16;
typedef __attribute__((ext_vector_type(8))) unsigned short us8;

__device__ inline unsigned short f2bf(float f) {
  unsigned int u = __builtin_bit_cast(unsigned int, f);
  unsigned int r = (u + 0x7FFFu + ((u >> 16) & 1u)) >> 16;
  return (unsigned short)r;
}

__device__ inline float bf2f(unsigned short u) {
  return __builtin_bit_cast(float, (unsigned int)u << 16);
}

__device__ inline bf16x8 ld8(const unsigned short* p) {
  us8 v = *(const us8*)p;
  return __builtin_bit_cast(bf16x8, v);
}

// ---------------------------------------------------------------------------
// K0: broadcast priors (P,78) -> (B,P,78)
// ---------------------------------------------------------------------------
__global__ __launch_bounds__(256)
void k_init_priors(const float* __restrict__ priors, float* __restrict__ out) {
  int idx = blockIdx.x * 256 + threadIdx.x;
  if (idx < BB * PP * 78) out[idx] = priors[idx % (PP * 78)];
}

// ---------------------------------------------------------------------------
// K0b: fmap [B][C][H][W] fp32 -> fmT [B][H*W][C] bf16 (pixel-major).
// ---------------------------------------------------------------------------
__global__ __launch_bounds__(256)
void k_transpose(const float* __restrict__ fmap, int HW, int tiles_per_b,
                 unsigned short* __restrict__ fmT) {
  __shared__ unsigned short Ls[64][66];
  int b = blockIdx.x / tiles_per_b;
  int p0 = (blockIdx.x % tiles_per_b) * 64;
  int tid = threadIdx.x;
  for (int idx = tid; idx < 4096; idx += 256) {
    int c = idx >> 6, pos = idx & 63;
    Ls[c][pos] = f2bf(fmap[((size_t)b * 64 + c) * HW + p0 + pos]);
  }
  __syncthreads();
  for (int idx = tid; idx < 4096; idx += 256) {
    int pos = idx >> 6, c = idx & 63;
    fmT[((size_t)b * HW + p0 + pos) * 64 + c] = Ls[c][pos];
  }
}

// ---------------------------------------------------------------------------
// Repack weights to bf16 MFMA-A layouts.
// Sections: Wr[82944] | Wc2[165888] (32x32-frag pre-swizzled) | fw[147456] |
//           wm[22528] = w1c,w2c,w1r,w2r (4x4096), hc (16x64), hr (80x64)
// Wc2: per stage region (off {0,27648,82944}), slice_id = i*27 + t*3 + s,
//      frag (slice_id*2+m)*512 + lane*8 + j  <->  W[o=m*32+(lane&31)]
//      [c = s*16 + (lane>>5)*8 + j], tap t, group i.
// ---------------------------------------------------------------------------
__global__ __launch_bounds__(256)
void k_repack(const float* __restrict__ cw,
              const float* __restrict__ c0, const float* __restrict__ c1,
              const float* __restrict__ c2, const float* __restrict__ fcw,
              const float* __restrict__ clsW, const float* __restrict__ regW,
              const float* __restrict__ chw, const float* __restrict__ rhw,
              unsigned short* __restrict__ Wr, unsigned short* __restrict__ Wc,
              unsigned short* __restrict__ fw, unsigned short* __restrict__ wm) {
  int idx = blockIdx.x * 256 + threadIdx.x;
  if (idx < 82944) {
    int c = idx & 63; int t = idx >> 6; int o = t % 48; t /= 48;
    int k = t % 9; int s = t / 9;
    Wr[idx] = f2bf(cw[((size_t)(s * 48 + o) * 64 + c) * 9 + k]);
  } else if (idx < 82944 + 165888) {
    int r = idx - 82944;
    int st, base, NC;
    if (r < 27648)            { st = 0; base = 0;     NC = 1; }
    else if (r < 82944)       { st = 1; base = 27648; NC = 2; }
    else                      { st = 2; base = 82944; NC = 3; }
    int r2 = r - base;
    int slice_id = r2 >> 10;
    int m = (r2 >> 9) & 1;
    int lane = (r2 >> 3) & 63;
    int j = r2 & 7;
    int i = slice_id / 27;
    int rem = slice_id % 27;
    int t = rem / 3;
    int s = rem % 3;
    int o = m * 32 + (lane & 31);
    int c = s * 16 + (lane >> 5) * 8 + j;
    const float* src = (st == 0) ? c0 : (st == 1) ? c1 : c2;
    Wc[r] = f2bf(src[((size_t)o * (NC * 48) + i * 48 + c) * 9 + t]);
  } else if (idx < 82944 + 165888 + 147456) {
    int q = idx - (82944 + 165888);
    int h = q / 2304; int kp = q % 2304; int j = kp >> 6; int c = kp & 63;
    fw[q] = f2bf(fcw[(size_t)h * 2304 + c * 36 + j]);
  } else if (idx < 82944 + 165888 + 147456 + 22528) {
    int q = idx - (82944 + 165888 + 147456);
    unsigned short v;
    if (q < 4096)        v = f2bf(clsW[q]);
    else if (q < 8192)   v = f2bf(clsW[4096 + (q - 4096)]);
    else if (q < 12288)  v = f2bf(regW[q - 8192]);
    else if (q < 16384)  v = f2bf(regW[4096 + (q - 12288)]);
    else if (q < 17408) { int r = q - 16384; int o = r >> 6, c = r & 63;
                          v = (o < 2) ? f2bf(chw[o * 64 + c]) : (unsigned short)0; }
    else                { int r = q - 17408; int o = r >> 6, c = r & 63;
                          v = (o < 76) ? f2bf(rhw[o * 64 + c]) : (unsigned short)0; }
    wm[q] = v;
  }
}

// ---------------------------------------------------------------------------
// K2: key/value in MFMA-B layouts. Block = (b, 64-key tile); 256 blocks.
// ---------------------------------------------------------------------------
__global__ __launch_bounds__(256)
void k_kv(const unsigned short* __restrict__ fmT, int H, int W,
          const float* __restrict__ fkey_w, const float* __restrict__ fkey_scale,
          const float* __restrict__ fkey_shift,
          const float* __restrict__ fval_w, const float* __restrict__ fval_b,
          unsigned short* __restrict__ keyT, unsigned short* __restrict__ valB) {
  __shared__ float pix[64][68];
  __shared__ __align__(16) unsigned short kout[64][80];
  __shared__ __align__(16) unsigned short vout[64][80];
  int tid = threadIdx.x;
  int b = blockIdx.x >> 2;
  int k0 = (blockIdx.x & 3) * 64;

  {
    int key = tid >> 2, cq = tid & 3;
    int k = k0 + key;
    float v[16];
    if (k < 250) {
      int r = k / 25, c2 = k % 25;
      int iy = (r * H) / 10, ix = (c2 * W) / 25;
      const unsigned short* src = fmT + ((size_t)b * H * W + iy * W + ix) * 64 + cq * 16;
      us8 a = *(const us8*)src;
      us8 bb = *(const us8*)(src + 8);
#pragma unroll
      for (int e = 0; e < 8; ++e) { v[e] = bf2f(a[e]); v[8 + e] = bf2f(bb[e]); }
    } else {
#pragma unroll
      for (int e = 0; e < 16; ++e) v[e] = 0.f;
    }
#pragma unroll
    for (int e = 0; e < 16; ++e) pix[key][cq * 16 + e] = v[e];
  }
  __syncthreads();

  {
    int o = tid >> 2, kq = tid & 3;
    float ak[16], av[16];
#pragma unroll
    for (int kk = 0; kk < 16; ++kk) { ak[kk] = 0.f; av[kk] = 0.f; }
    for (int c = 0; c < 64; ++c) {
      float wk = fkey_w[o * 64 + c], wvv = fval_w[o * 64 + c];
#pragma unroll
      for (int kk = 0; kk < 16; ++kk) {
        float pv = pix[kq * 16 + kk][c];
        ak[kk] += pv * wk; av[kk] += pv * wvv;
      }
    }
    float sc_ = fkey_scale[o], sh = fkey_shift[o], vb_ = fval_b[o];
#pragma unroll
    for (int kk = 0; kk < 16; ++kk) {
      int k = kq * 16 + kk;
      float kf = ak[kk] * sc_ + sh; kf = kf > 0.f ? kf : 0.f;
      kout[k][o] = f2bf(kf);
      vout[o][k] = f2bf(av[kk] + vb_);
    }
  }
  __syncthreads();

  {
    int row = tid >> 2, oq = tid & 3;
    *(us8*)(keyT + ((size_t)b * 256 + k0 + row) * 64 + oq * 16)     = *(us8*)&kout[row][oq * 16];
    *(us8*)(keyT + ((size_t)b * 256 + k0 + row) * 64 + oq * 16 + 8) = *(us8*)&kout[row][oq * 16 + 8];
    *(us8*)(valB + ((size_t)b * 64 + row) * 256 + k0 + oq * 16)     = *(us8*)&vout[row][oq * 16];
    *(us8*)(valB + ((size_t)b * 64 + row) * 256 + k0 + oq * 16 + 8) = *(us8*)&vout[row][oq * 16 + 8];
  }
}

// ---------------------------------------------------------------------------
// K1a: fused gather + conv_s (MFMA 16x16x32). Unchanged from round 4.
// ---------------------------------------------------------------------------
template <int STAGE>
__global__ __launch_bounds__(256)
void k_gatherconv(const unsigned short* __restrict__ fmT,
                  const float* __restrict__ priors_cur,
                  const unsigned short* __restrict__ Wr,
                  const float* __restrict__ cscale, const float* __restrict__ cshift,
                  unsigned short* __restrict__ cfg) {
  constexpr int H = (STAGE == 0) ? 64 : (STAGE == 1) ? 32 : 16;
  constexpr int W = (STAGE == 0) ? 80 : (STAGE == 1) ? 40 : 20;
  constexpr int HW = H * W;

  __shared__ float posx[8][36], posy[8][36];
  __shared__ __align__(16) unsigned short Xs[360][64];

  int tid = threadIdx.x;
  int r0 = blockIdx.x * 8;

  for (int idx = tid; idx < 288; idx += 256) {
    int q = idx / 36, j = idx % 36;
    int bp = r0 + q;
    int k = 35 - j;
    int sx = (int)(((float)k / 35.0f) * 71.0f);
    float px = priors_cur[(size_t)bp * 78 + 6 + sx];
    posx[q][j] = px * (float)(W - 1);
    float fy = 1.0f - (float)sx / 71.0f;
    posy[q][j] = fy * (float)(H - 1);
  }
  __syncthreads();

  for (int idx = tid; idx < 360 * 8; idx += 256) {
    int row = idx >> 3, ch8 = idx & 7;
    int p = row - 4;
    unsigned short pk[8] = {0, 0, 0, 0, 0, 0, 0, 0};
    if (p >= 0 && p < 352) {
      int q = p / 44, x = p % 44;
      if (x >= 4 && x < 40) {
        int j = x - 4;
        int b = (r0 + q) / PP;
        float fx = posx[q][j];
        float fy = posy[q][j];
        float x0 = floorf(fx), y0 = floorf(fy);
        float wx = fx - x0, wy = fy - y0;
        float xs2[2] = {x0, x0 + 1.f};
        float ys2[2] = {y0, y0 + 1.f};
        float wxs[2] = {1.f - wx, wx};
        float wys[2] = {1.f - wy, wy};
        float accf[8] = {0.f, 0.f, 0.f, 0.f, 0.f, 0.f, 0.f, 0.f};
#pragma unroll
        for (int ty = 0; ty < 2; ++ty)
#pragma unroll
          for (int tx = 0; tx < 2; ++tx) {
            float xf = xs2[tx], yf = ys2[ty];
            bool v = (xf >= 0.f) && (xf <= (float)(W - 1)) &&
                     (yf >= 0.f) && (yf <= (float)(H - 1));
            int xi = (int)fminf(fmaxf(xf, 0.f), (float)(W - 1));
            int yi = (int)fminf(fmaxf(yf, 0.f), (float)(H - 1));
            float wgt = v ? (wxs[tx] * wys[ty]) : 0.f;
            const us8 vv = *(const us8*)(fmT + ((size_t)b * HW + yi * W + xi) * 64 + ch8 * 8);
#pragma unroll
            for (int e = 0; e < 8; ++e) accf[e] += wgt * bf2f(vv[e]);
          }
#pragma unroll
        for (int e = 0; e < 8; ++e) pk[e] = f2bf(accf[e]);
      }
    }
    int pc = ch8 ^ (row & 7);
    *(us8*)&Xs[row][pc * 8] = *(us8*)pk;
  }
  __syncthreads();

  int wv = tid >> 6, lane = tid & 63, l15 = lane & 15, quad = lane >> 4;
  f32x4 acc[3][6];
#pragma unroll
  for (int m = 0; m < 3; ++m)
#pragma unroll
    for (int s = 0; s < 6; ++s) acc[m][s] = (f32x4)0.f;

  for (int k = 0; k < 9; ++k) {
#pragma unroll
    for (int kk = 0; kk < 2; ++kk) {
      bf16x8 af[3];
#pragma unroll
      for (int m = 0; m < 3; ++m)
        af[m] = ld8(Wr + ((size_t)(k * 48 + m * 16 + l15)) * 64 + kk * 32 + quad * 8);
#pragma unroll
      for (int s = 0; s < 6; ++s) {
        int nt = wv + 4 * s;
        if (nt < 22) {
          int row = nt * 16 + l15 + k;
          int pc = (kk * 4 + quad) ^ (row & 7);
          bf16x8 bfr = ld8(&Xs[row][pc * 8]);
#pragma unroll
          for (int m = 0; m < 3; ++m)
            acc[m][s] = __builtin_amdgcn_mfma_f32_16x16x32_bf16(af[m], bfr, acc[m][s], 0, 0, 0);
        }
      }
    }
  }

#pragma unroll
  for (int s = 0; s < 6; ++s) {
    int nt = wv + 4 * s;
    if (nt < 22) {
      int p = nt * 16 + l15;
      int q = p / 44, x = p % 44;
      if (x >= 4 && x < 40) {
        int bp = r0 + q;
#pragma unroll
        for (int m = 0; m < 3; ++m) {
          int o0 = m * 16 + quad * 4;
          unsigned short pk[4];
#pragma unroll
          for (int rg = 0; rg < 4; ++rg) {
            float v = acc[m][s][rg] * cscale[o0 + rg] + cshift[o0 + rg];
            pk[rg] = f2bf(v > 0.f ? v : 0.f);
          }
          *(uint2*)(cfg + ((size_t)bp * 36 + (x - 4)) * 48 + o0) = *(uint2*)pk;
        }
      }
    }
  }
}

// ---------------------------------------------------------------------------
// K1b: cat conv with 32x32x16 MFMA. M=64 (2 tiles), N=352 (11 tiles, split
// 3/3/3/2 over waves), K = NC*9 taps * 3 slices of 16 (48 real ch, no pad).
// A-frags pre-swizzled (lane-contiguous); B from swizzled LDS (even slot
// spread -> no extra bank conflicts). C/D: col=lane&31,
// row=(reg&3)+8*(reg>>2)+4*(lane>>5)   [m74/m101 verified].
// ---------------------------------------------------------------------------
template <int STAGE>
__global__ __launch_bounds__(256)
void k_cat(const unsigned short* __restrict__ cfg_all,
           const unsigned short* __restrict__ Wc,       // this stage's region
           const float* __restrict__ kscale, const float* __restrict__ kshift,
           unsigned short* __restrict__ catf) {
  constexpr int NC = STAGE + 1;
  __shared__ __align__(16) unsigned short cfs[360][64];
  int tid = threadIdx.x;
  int r0 = blockIdx.x * 8;
  int wv = tid >> 6, lane = tid & 63;
  int l31 = lane & 31, half = lane >> 5;

  int nt0 = wv * 3;
  int ntn = (wv < 3) ? 3 : 2;       // 11 n-tiles total

  f32x16 acc[2][3];
#pragma unroll
  for (int m = 0; m < 2; ++m)
#pragma unroll
    for (int n = 0; n < 3; ++n) acc[m][n] = (f32x16)0.f;

#pragma unroll
  for (int i = 0; i < NC; ++i) {
    __syncthreads();
    for (int idx = tid; idx < 2160; idx += 256) {
      int row = idx / 6, ch = idx % 6;
      int p = row - 4;
      us8 v = (us8)(unsigned short)0;
      if (p >= 0 && p < 352) {
        int q = p / 44, x = p % 44;
        if (x >= 4 && x < 40) {
          v = *(const us8*)(cfg_all + (size_t)i * (12288ull * 36 * 48) +
                            ((size_t)(r0 + q) * 36 + (x - 4)) * 48 + ch * 8);
        }
      }
      *(us8*)&cfs[row][((ch ^ (row & 7)) * 8)] = v;
    }
    __syncthreads();

    for (int t = 0; t < 9; ++t) {
#pragma unroll
      for (int s = 0; s < 3; ++s) {
        int slice_id = i * 27 + t * 3 + s;
        bf16x8 a0 = ld8(Wc + (size_t)(slice_id * 2 + 0) * 512 + lane * 8);
        bf16x8 a1 = ld8(Wc + (size_t)(slice_id * 2 + 1) * 512 + lane * 8);
#pragma unroll
        for (int n = 0; n < 3; ++n) {
          if (n < ntn) {
            int row = (nt0 + n) * 32 + l31 + t;
            int q = (s * 2 + half) ^ (row & 7);
            bf16x8 b = ld8(&cfs[row][q * 8]);
            acc[0][n] = __builtin_amdgcn_mfma_f32_32x32x16_bf16(a0, b, acc[0][n], 0, 0, 0);
            acc[1][n] = __builtin_amdgcn_mfma_f32_32x32x16_bf16(a1, b, acc[1][n], 0, 0, 0);
          }
        }
      }
    }
  }

#pragma unroll
  for (int n = 0; n < 3; ++n) {
    if (n < ntn) {
      int p = (nt0 + n) * 32 + l31;
      int q = p / 44, x = p % 44;
      if (x >= 4 && x < 40) {
        int bp = r0 + q;
        unsigned short* dst = catf + ((size_t)bp * 36 + (x - 4)) * 64;
#pragma unroll
        for (int m = 0; m < 2; ++m) {
#pragma unroll
          for (int r = 0; r < 4; ++r) {
            int o0 = m * 32 + r * 8 + half * 4;
            unsigned short pk[4];
#pragma unroll
            for (int g = 0; g < 4; ++g) {
              int o = o0 + g;
              float v = acc[m][n][r * 4 + g] * kscale[o] + kshift[o];
              pk[g] = f2bf(v > 0.f ? v : 0.f);
            }
            *(uint2*)(dst + o0) = *(uint2*)pk;
          }
        }
      }
    }
  }
}

// ---------------------------------------------------------------------------
// K1c: fc GEMM + bias + LayerNorm + relu.
// ---------------------------------------------------------------------------
__global__ __launch_bounds__(256)
void k_fc(const unsigned short* __restrict__ catf,
          const unsigned short* __restrict__ fw,
          const float* __restrict__ fc_b,
          const float* __restrict__ ln_g, const float* __restrict__ ln_b,
          float* __restrict__ roi_fc) {
  __shared__ __align__(16) float fcb[64][68];
  int tid = threadIdx.x, wv = tid >> 6, lane = tid & 63, l15 = lane & 15, quad = lane >> 4;
  int nbase = blockIdx.x * 64 + wv * 16;

  f32x4 acc[4];
#pragma unroll
  for (int m = 0; m < 4; ++m) acc[m] = (f32x4)0.f;

  for (int ks = 0; ks < 72; ++ks) {
    int j = ks >> 1, ch = (ks & 1) * 32;
    bf16x8 bfr = ld8(catf + ((size_t)(nbase + l15) * 36 + j) * 64 + ch + quad * 8);
#pragma unroll
    for (int m = 0; m < 4; ++m) {
      bf16x8 af = ld8(fw + (size_t)(m * 16 + l15) * 2304 + ks * 32 + quad * 8);
      acc[m] = __builtin_amdgcn_mfma_f32_16x16x32_bf16(af, bfr, acc[m], 0, 0, 0);
    }
  }

#pragma unroll
  for (int m = 0; m < 4; ++m) {
    f32x4 v;
#pragma unroll
    for (int rg = 0; rg < 4; ++rg) v[rg] = acc[m][rg] + fc_b[m * 16 + quad * 4 + rg];
    *(f32x4*)&fcb[wv * 16 + l15][m * 16 + quad * 4] = v;
  }
  __syncthreads();

  for (int rr = 0; rr < 16; ++rr) {
    int rl = wv * 16 + rr;
    float y = fcb[rl][lane];
    float s = y;
#pragma unroll
    for (int off = 32; off > 0; off >>= 1) s += __shfl_xor(s, off, 64);
    float mu = s * (1.f / 64.f);
    float d = y - mu;
    float v2 = d * d;
#pragma unroll
    for (int off = 32; off > 0; off >>= 1) v2 += __shfl_xor(v2, off, 64);
    float var = v2 * (1.f / 64.f);
    float r = d / sqrtf(var + 1e-5f) * ln_g[lane] + ln_b[lane];
    roi_fc[(size_t)(blockIdx.x * 64 + rl) * 64 + lane] = r > 0.f ? r : 0.f;
  }
}

// ---------------------------------------------------------------------------
// helper: one 16(M)x16(N)x64(K) GEMM tile.
// ---------------------------------------------------------------------------
__device__ inline f32x4 gemm_tile(const unsigned short* __restrict__ Wrow0,
                                  const unsigned short* Xl, int l15, int quad) {
  f32x4 a = (f32x4)0.f;
#pragma unroll
  for (int kk = 0; kk < 2; ++kk) {
    bf16x8 af = ld8(Wrow0 + (size_t)l15 * 64 + kk * 32 + quad * 8);
    bf16x8 bx = ld8(Xl + l15 * 64 + (((kk * 4 + quad) ^ (l15 & 7)) * 8));
    a = __builtin_amdgcn_mfma_f32_16x16x32_bf16(af, bx, a, 0, 0, 0);
  }
  return a;
}

// ---------------------------------------------------------------------------
// K3: batched attention + MLP heads + tan epilogue, all MFMA.
// ---------------------------------------------------------------------------
__global__ __launch_bounds__(256)
void k_att2(const float* __restrict__ roi_fc,
            const unsigned short* __restrict__ keyT,
            const unsigned short* __restrict__ valB,
            const float* __restrict__ fq_w, const float* __restrict__ fq_b,
            const float* __restrict__ attW_w, const float* __restrict__ attW_b,
            const unsigned short* __restrict__ wm,
            const float* __restrict__ cls_mlp_b, const float* __restrict__ reg_mlp_b,
            const float* __restrict__ cls_head_b, const float* __restrict__ reg_head_b,
            const float* __restrict__ priors_cur,
            float* __restrict__ priors_next,
            float* __restrict__ preds) {
  __shared__ __align__(16) unsigned char smem[8192 + 4 * 4608 + 4 * 8192];
  unsigned short* qx = (unsigned short*)smem;
  unsigned char* Bb = smem + 8192;
  unsigned char* Cb = smem + 8192 + 4 * 4608;

  int tid = threadIdx.x, wv = tid >> 6, lane = tid & 63;
  int l15 = lane & 15, quad = lane >> 4;
  int rb = blockIdx.x * 64;
  int b = rb / PP;
  int p_base = rb % PP;

  float* rf = (float*)(Bb + wv * 4608);
  unsigned short* hA = (unsigned short*)(Bb + wv * 4608);
  unsigned short* hB = (unsigned short*)(Bb + wv * 4608 + 2304);
  unsigned short* simw = (unsigned short*)(Cb + wv * 8192);
  unsigned short* rego = (unsigned short*)(Cb + wv * 8192);
  unsigned short* clso = (unsigned short*)(Cb + wv * 8192 + 2560);

  for (int it = tid; it < 512; it += 256) {
    int row = it >> 3, ch = it & 7;
    const float* src = roi_fc + (size_t)(rb + row) * 64 + ch * 8;
    float v[8];
#pragma unroll
    for (int e = 0; e < 8; ++e) v[e] = src[e];
    float* rfw = (float*)(Bb + (row >> 4) * 4608);
#pragma unroll
    for (int e = 0; e < 8; ++e) rfw[(row & 15) * 68 + ch * 8 + e] = v[e];
    int p = p_base + row;
    float qw = fq_w[p], qb = fq_b[p];
    unsigned short pk[8];
#pragma unroll
    for (int e = 0; e < 8; ++e) {
      float q = v[e] * qw + qb;
      pk[e] = f2bf(q > 0.f ? q : 0.f);
    }
    *(us8*)&qx[row * 64 + ((ch ^ (row & 7)) * 8)] = *(us8*)pk;
  }
  __syncthreads();

  f32x4 sc[16];
#pragma unroll
  for (int nt = 0; nt < 16; ++nt) sc[nt] = (f32x4)0.f;
  const unsigned short* kb = keyT + (size_t)b * 256 * 64;
#pragma unroll
  for (int kk = 0; kk < 2; ++kk) {
    bf16x8 af = ld8(&qx[(wv * 16 + l15) * 64 + (((kk * 4 + quad) ^ (l15 & 7)) * 8)]);
#pragma unroll
    for (int nt = 0; nt < 16; ++nt) {
      bf16x8 bf_ = ld8(kb + (size_t)(nt * 16 + l15) * 64 + kk * 32 + quad * 8);
      sc[nt] = __builtin_amdgcn_mfma_f32_16x16x32_bf16(af, bf_, sc[nt], 0, 0, 0);
    }
  }
  float mx[4] = {-1e30f, -1e30f, -1e30f, -1e30f};
#pragma unroll
  for (int nt = 0; nt < 16; ++nt)
#pragma unroll
    for (int rg = 0; rg < 4; ++rg) {
      float s = sc[nt][rg] * 0.125f;
      if (nt == 15 && l15 >= 10) s = -1e30f;
      sc[nt][rg] = s;
      mx[rg] = fmaxf(mx[rg], s);
    }
#pragma unroll
  for (int rg = 0; rg < 4; ++rg)
#pragma unroll
    for (int off = 1; off < 16; off <<= 1)
      mx[rg] = fmaxf(mx[rg], __shfl_xor(mx[rg], off, 64));
  float sm[4] = {0.f, 0.f, 0.f, 0.f};
#pragma unroll
  for (int nt = 0; nt < 16; ++nt)
#pragma unroll
    for (int rg = 0; rg < 4; ++rg) {
      float e = expf(sc[nt][rg] - mx[rg]);
      sc[nt][rg] = e;
      sm[rg] += e;
    }
#pragma unroll
  for (int rg = 0; rg < 4; ++rg)
#pragma unroll
    for (int off = 1; off < 16; off <<= 1)
      sm[rg] += __shfl_xor(sm[rg], off, 64);
  float rs[4];
#pragma unroll
  for (int rg = 0; rg < 4; ++rg) rs[rg] = 1.f / sm[rg];
#pragma unroll
  for (int nt = 0; nt < 16; ++nt)
#pragma unroll
    for (int rg = 0; rg < 4; ++rg) {
      int row = quad * 4 + rg, col = nt * 16 + l15;
      simw[row * 256 + (((col >> 3) ^ (row & 7)) * 8) + (col & 7)] = f2bf(sc[nt][rg] * rs[rg]);
    }

  f32x4 cv[4];
#pragma unroll
  for (int nt = 0; nt < 4; ++nt) cv[nt] = (f32x4)0.f;
  const unsigned short* vb = valB + (size_t)b * 64 * 256;
#pragma unroll
  for (int ks = 0; ks < 8; ++ks) {
    bf16x8 af = ld8(&simw[l15 * 256 + (((ks * 4 + quad) ^ (l15 & 7)) * 8)]);
#pragma unroll
    for (int nt = 0; nt < 4; ++nt) {
      bf16x8 bf_ = ld8(vb + (size_t)(nt * 16 + l15) * 256 + ks * 32 + quad * 8);
      cv[nt] = __builtin_amdgcn_mfma_f32_16x16x32_bf16(af, bf_, cv[nt], 0, 0, 0);
    }
  }
#pragma unroll
  for (int rg = 0; rg < 4; ++rg) {
    int row = quad * 4 + rg;
    int p = p_base + wv * 16 + row;
    float aw = attW_w[p], ab = attW_b[p];
#pragma unroll
    for (int nt = 0; nt < 4; ++nt) {
      int c = nt * 16 + l15;
      float xv = rf[row * 68 + c] + cv[nt][rg] * aw + ab;
      qx[(wv * 16 + row) * 64 + (((c >> 3) ^ (row & 7)) * 8) + (c & 7)] = f2bf(xv);
    }
  }

  const unsigned short* xw = qx + wv * 16 * 64;
#pragma unroll
  for (int mt = 0; mt < 4; ++mt) {
    f32x4 a = gemm_tile(wm + 0 + mt * 1024, xw, l15, quad);
#pragma unroll
    for (int rg = 0; rg < 4; ++rg) {
      int o = mt * 16 + quad * 4 + rg;
      float v = a[rg] + cls_mlp_b[o]; v = v > 0.f ? v : 0.f;
      hA[l15 * 64 + (((o >> 3) ^ (l15 & 7)) * 8) + (o & 7)] = f2bf(v);
    }
  }
#pragma unroll
  for (int mt = 0; mt < 4; ++mt) {
    f32x4 a = gemm_tile(wm + 4096 + mt * 1024, hA, l15, quad);
#pragma unroll
    for (int rg = 0; rg < 4; ++rg) {
      int o = mt * 16 + quad * 4 + rg;
      float v = a[rg] + cls_mlp_b[64 + o]; v = v > 0.f ? v : 0.f;
      hB[l15 * 64 + (((o >> 3) ^ (l15 & 7)) * 8) + (o & 7)] = f2bf(v);
    }
  }
  {
    f32x4 a = gemm_tile(wm + 16384, hB, l15, quad);
#pragma unroll
    for (int rg = 0; rg < 4; ++rg) {
      int o = quad * 4 + rg;
      if (o < 2) clso[l15 * 2 + o] = f2bf(a[rg] + cls_head_b[o]);
    }
  }
#pragma unroll
  for (int mt = 0; mt < 4; ++mt) {
    f32x4 a = gemm_tile(wm + 8192 + mt * 1024, xw, l15, quad);
#pragma unroll
    for (int rg = 0; rg < 4; ++rg) {
      int o = mt * 16 + quad * 4 + rg;
      float v = a[rg] + reg_mlp_b[o]; v = v > 0.f ? v : 0.f;
      hA[l15 * 64 + (((o >> 3) ^ (l15 & 7)) * 8) + (o & 7)] = f2bf(v);
    }
  }
#pragma unroll
  for (int mt = 0; mt < 4; ++mt) {
    f32x4 a = gemm_tile(wm + 12288 + mt * 1024, hA, l15, quad);
#pragma unroll
    for (int rg = 0; rg < 4; ++rg) {
      int o = mt * 16 + quad * 4 + rg;
      float v = a[rg] + reg_mlp_b[64 + o]; v = v > 0.f ? v : 0.f;
      hB[l15 * 64 + (((o >> 3) ^ (l15 & 7)) * 8) + (o & 7)] = f2bf(v);
    }
  }
#pragma unroll
  for (int mt = 0; mt < 5; ++mt) {
    f32x4 a = gemm_tile(wm + 17408 + mt * 1024, hB, l15, quad);
#pragma unroll
    for (int rg = 0; rg < 4; ++rg) {
      int o = mt * 16 + quad * 4 + rg;
      if (o < 76) rego[l15 * 80 + o] = f2bf(a[rg] + reg_head_b[o]);
    }
  }

  {
    int p_local = lane >> 2, g = lane & 3;
    int bp = rb + wv * 16 + p_local;
    const float* pc = priors_cur + (size_t)bp * 78;
    float r0v = bf2f(rego[p_local * 80 + 0]);
    float r1v = bf2f(rego[p_local * 80 + 1]);
    float r2v = bf2f(rego[p_local * 80 + 2]);
    float r3v = bf2f(rego[p_local * 80 + 3]);
    float p0 = pc[2] + r0v;
    float p1 = pc[3] + r1v;
    float p2 = pc[4] + r2v;
    float* po = preds + (size_t)bp * 78;
    float* pn = priors_next ? priors_next + (size_t)bp * 78 : nullptr;
    if (g == 0) {
      float c0v = bf2f(clso[p_local * 2 + 0]);
      float c1v = bf2f(clso[p_local * 2 + 1]);
      po[0] = c0v; po[1] = c1v;
      po[2] = p0; po[3] = p1; po[4] = p2; po[5] = r3v;
      if (pn) { pn[0] = c0v; pn[1] = c1v; pn[2] = p0; pn[3] = p1; pn[4] = p2; pn[5] = r3v; }
    }
    float t = tanf(p2 * PI_F + 1e-5f);
    float inv_t = 512.f / t;
#pragma unroll 2
    for (int i = g * 18; i < g * 18 + 18; ++i) {
      float py = 1.0f - (float)i / 71.0f;
      float offs = (p1 * 639.0f + (1.0f - py - p0) * inv_t) * (1.0f / 639.0f);
      po[6 + i] = offs + bf2f(rego[p_local * 80 + 4 + i]);
      if (pn) pn[6 + i] = offs;
    }
  }
}

// ---------------------------------------------------------------------------
extern "C" void kernel_launch(void* const* d_in, const int* in_sizes, int n_in,
                              void* d_out, int out_size, void* d_ws, size_t ws_size,
                              hipStream_t stream) {
  (void)in_sizes; (void)n_in; (void)out_size; (void)ws_size;
  const float* feat[3] = {(const float*)d_in[0], (const float*)d_in[1], (const float*)d_in[2]};
  const float* priors      = (const float*)d_in[3];
  const float* convs_w     = (const float*)d_in[4];
  const float* convs_scale = (const float*)d_in[5];
  const float* convs_shift = (const float*)d_in[6];
  const float* cat_w[3]    = {(const float*)d_in[7], (const float*)d_in[8], (const float*)d_in[9]};
  const float* cat_scale   = (const float*)d_in[10];
  const float* cat_shift   = (const float*)d_in[11];
  const float* fkey_w      = (const float*)d_in[12];
  const float* fkey_scale  = (const float*)d_in[13];
  const float* fkey_shift  = (const float*)d_in[14];
  const float* fval_w      = (const float*)d_in[15];
  const float* fval_b      = (const float*)d_in[16];
  const float* fq_w        = (const float*)d_in[17];
  const float* fq_b        = (const float*)d_in[18];
  const float* attW_w      = (const float*)d_in[19];
  const float* attW_b      = (const float*)d_in[20];
  const float* fc_w        = (const float*)d_in[21];
  const float* fc_b        = (const float*)d_in[22];
  const float* ln_g        = (const float*)d_in[23];
  const float* ln_b        = (const float*)d_in[24];
  const float* cls_mlp_w   = (const float*)d_in[25];
  const float* cls_mlp_b   = (const float*)d_in[26];
  const float* reg_mlp_w   = (const float*)d_in[27];
  const float* reg_mlp_b   = (const float*)d_in[28];
  const float* cls_head_w  = (const float*)d_in[29];
  const float* cls_head_b  = (const float*)d_in[30];
  const float* reg_head_w  = (const float*)d_in[31];
  const float* reg_head_b  = (const float*)d_in[32];
  float* out = (float*)d_out;

  char* wp = (char*)d_ws;
  auto alloc = [&](size_t bytes) { char* r = wp; wp += (bytes + 255) & ~(size_t)255; return r; };

  float* priA   = (float*)alloc((size_t)BB * PP * 78 * 4);
  float* priB   = (float*)alloc((size_t)BB * PP * 78 * 4);
  float* roi_fc = (float*)alloc((size_t)BB * PP * 64 * 4);
  unsigned short* keyT = (unsigned short*)alloc((size_t)BB * 256 * 64 * 2);
  unsigned short* valB = (unsigned short*)alloc((size_t)BB * 64 * 256 * 2);
  unsigned short* Wr   = (unsigned short*)alloc(82944ull * 2);
  unsigned short* Wc   = (unsigned short*)alloc(165888ull * 2);
  unsigned short* fw   = (unsigned short*)alloc(147456ull * 2);
  unsigned short* wm   = (unsigned short*)alloc(22528ull * 2);
  unsigned short* cfg  = (unsigned short*)alloc(3ull * 12288 * 36 * 48 * 2);
  unsigned short* catf = (unsigned short*)alloc(12288ull * 36 * 64 * 2);
  unsigned short* fmT  = (unsigned short*)alloc((size_t)BB * 64 * 80 * 64 * 2);

  const int HW[3][2] = {{64, 80}, {32, 40}, {16, 20}};
  const size_t wcoff[3] = {0, 27648, 82944};

  k_init_priors<<<dim3((BB * PP * 78 + 255) / 256), dim3(256), 0, stream>>>(priors, priA);
  k_repack<<<dim3((418816 + 255) / 256), dim3(256), 0, stream>>>(
      convs_w, cat_w[0], cat_w[1], cat_w[2], fc_w,
      cls_mlp_w, reg_mlp_w, cls_head_w, reg_head_w, Wr, Wc, fw, wm);

  float* pcur = priA;
  float* pnext = priB;
  for (int s = 0; s < 3; ++s) {
    int H = HW[s][0], W = HW[s][1];
    int hw = H * W;
    int tiles = hw / 64;
    k_transpose<<<dim3(BB * tiles), dim3(256), 0, stream>>>(feat[s], hw, tiles, fmT);

    k_kv<<<dim3(BB * 4), dim3(256), 0, stream>>>(
        fmT, H, W, fkey_w, fkey_scale, fkey_shift, fval_w, fval_b, keyT, valB);

    if (s == 0) {
      k_gatherconv<0><<<dim3(1536), dim3(256), 0, stream>>>(
          fmT, pcur, Wr + 0 * 27648, convs_scale + 0, convs_shift + 0,
          cfg + 0ull * 12288 * 36 * 48);
      k_cat<0><<<dim3(1536), dim3(256), 0, stream>>>(
          cfg, Wc + wcoff[0], cat_scale + 0, cat_shift + 0, catf);
    } else if (s == 1) {
      k_gatherconv<1><<<dim3(1536), dim3(256), 0, stream>>>(
          fmT, pcur, Wr + 1 * 27648, convs_scale + 48, convs_shift + 48,
          cfg + 1ull * 12288 * 36 * 48);
      k_cat<1><<<dim3(1536), dim3(256), 0, stream>>>(
          cfg, Wc + wcoff[1], cat_scale + 64, cat_shift + 64, catf);
    } else {
      k_gatherconv<2><<<dim3(1536), dim3(256), 0, stream>>>(
          fmT, pcur, Wr + 2 * 27648, convs_scale + 96, convs_shift + 96,
          cfg + 2ull * 12288 * 36 * 48);
      k_cat<2><<<dim3(1536), dim3(256), 0, stream>>>(
          cfg, Wc + wcoff[2], cat_scale + 128, cat_shift + 128, catf);
    }

    k_fc<<<dim3(192), dim3(256), 0, stream>>>(catf, fw, fc_b, ln_g, ln_b, roi_fc);

    k_att2<<<dim3(192), dim3(256), 0, stream>>>(
        roi_fc, keyT, valB, fq_w, fq_b, attW_w, attW_b, wm,
        cls_mlp_b, reg_mlp_b, cls_head_b, reg_head_b,
        pcur, (s < 2) ? pnext : (float*)nullptr,
        out + (size_t)s * BB * PP * 78);

    float* tmp = pcur; pcur = pnext; pnext = tmp;
  }
}

// Round 6
// 929.685 us; speedup vs baseline: 9.4148x; 1.1105x over previous
//
#include <hip/hip_runtime.h>
#include <hip/hip_bf16.h>

#define BB 64
#define PP 192
#define SS 36
#define PI_F 3.14159265358979323846f

typedef __attribute__((ext_vector_type(8))) __bf16 bf16x8;
typedef __attribute__((ext_vector_type(4))) float f32x4;
typedef __attribute__((ext_vector_type(16))) float f32x16;
typedef __attribute__((ext_vector_type(8))) unsigned short us8;

__device__ inline unsigned short f2bf(float f) {
  unsigned int u = __builtin_bit_cast(unsigned int, f);
  unsigned int r = (u + 0x7FFFu + ((u >> 16) & 1u)) >> 16;
  return (unsigned short)r;
}

__device__ inline float bf2f(unsigned short u) {
  return __builtin_bit_cast(float, (unsigned int)u << 16);
}

__device__ inline bf16x8 ld8(const unsigned short* p) {
  us8 v = *(const us8*)p;
  return __builtin_bit_cast(bf16x8, v);
}

// ---------------------------------------------------------------------------
// K0: broadcast priors (P,78) -> (B,P,78)
// ---------------------------------------------------------------------------
__global__ __launch_bounds__(256)
void k_init_priors(const float* __restrict__ priors, float* __restrict__ out) {
  int idx = blockIdx.x * 256 + threadIdx.x;
  if (idx < BB * PP * 78) out[idx] = priors[idx % (PP * 78)];
}

// ---------------------------------------------------------------------------
// K0b: fmap [B][C][H][W] fp32 -> fmT [B][H*W][C] bf16 (pixel-major).
// ---------------------------------------------------------------------------
__global__ __launch_bounds__(256)
void k_transpose(const float* __restrict__ fmap, int HW, int tiles_per_b,
                 unsigned short* __restrict__ fmT) {
  __shared__ unsigned short Ls[64][66];
  int b = blockIdx.x / tiles_per_b;
  int p0 = (blockIdx.x % tiles_per_b) * 64;
  int tid = threadIdx.x;
  for (int idx = tid; idx < 4096; idx += 256) {
    int c = idx >> 6, pos = idx & 63;
    Ls[c][pos] = f2bf(fmap[((size_t)b * 64 + c) * HW + p0 + pos]);
  }
  __syncthreads();
  for (int idx = tid; idx < 4096; idx += 256) {
    int pos = idx >> 6, c = idx & 63;
    fmT[((size_t)b * HW + p0 + pos) * 64 + c] = Ls[c][pos];
  }
}

// ---------------------------------------------------------------------------
// Repack weights to bf16 MFMA-A layouts (same as round 5).
// ---------------------------------------------------------------------------
__global__ __launch_bounds__(256)
void k_repack(const float* __restrict__ cw,
              const float* __restrict__ c0, const float* __restrict__ c1,
              const float* __restrict__ c2, const float* __restrict__ fcw,
              const float* __restrict__ clsW, const float* __restrict__ regW,
              const float* __restrict__ chw, const float* __restrict__ rhw,
              unsigned short* __restrict__ Wr, unsigned short* __restrict__ Wc,
              unsigned short* __restrict__ fw, unsigned short* __restrict__ wm) {
  int idx = blockIdx.x * 256 + threadIdx.x;
  if (idx < 82944) {
    int c = idx & 63; int t = idx >> 6; int o = t % 48; t /= 48;
    int k = t % 9; int s = t / 9;
    Wr[idx] = f2bf(cw[((size_t)(s * 48 + o) * 64 + c) * 9 + k]);
  } else if (idx < 82944 + 165888) {
    int r = idx - 82944;
    int st, base, NC;
    if (r < 27648)            { st = 0; base = 0;     NC = 1; }
    else if (r < 82944)       { st = 1; base = 27648; NC = 2; }
    else                      { st = 2; base = 82944; NC = 3; }
    int r2 = r - base;
    int slice_id = r2 >> 10;
    int m = (r2 >> 9) & 1;
    int lane = (r2 >> 3) & 63;
    int j = r2 & 7;
    int i = slice_id / 27;
    int rem = slice_id % 27;
    int t = rem / 3;
    int s = rem % 3;
    int o = m * 32 + (lane & 31);
    int c = s * 16 + (lane >> 5) * 8 + j;
    const float* src = (st == 0) ? c0 : (st == 1) ? c1 : c2;
    Wc[r] = f2bf(src[((size_t)o * (NC * 48) + i * 48 + c) * 9 + t]);
  } else if (idx < 82944 + 165888 + 147456) {
    int q = idx - (82944 + 165888);
    int h = q / 2304; int kp = q % 2304; int j = kp >> 6; int c = kp & 63;
    fw[q] = f2bf(fcw[(size_t)h * 2304 + c * 36 + j]);
  } else if (idx < 82944 + 165888 + 147456 + 22528) {
    int q = idx - (82944 + 165888 + 147456);
    unsigned short v;
    if (q < 4096)        v = f2bf(clsW[q]);
    else if (q < 8192)   v = f2bf(clsW[4096 + (q - 4096)]);
    else if (q < 12288)  v = f2bf(regW[q - 8192]);
    else if (q < 16384)  v = f2bf(regW[4096 + (q - 12288)]);
    else if (q < 17408) { int r = q - 16384; int o = r >> 6, c = r & 63;
                          v = (o < 2) ? f2bf(chw[o * 64 + c]) : (unsigned short)0; }
    else                { int r = q - 17408; int o = r >> 6, c = r & 63;
                          v = (o < 76) ? f2bf(rhw[o * 64 + c]) : (unsigned short)0; }
    wm[q] = v;
  }
}

// ---------------------------------------------------------------------------
// K2: key/value in MFMA-B layouts. Block = (b, 64-key tile); 256 blocks.
// ---------------------------------------------------------------------------
__global__ __launch_bounds__(256)
void k_kv(const unsigned short* __restrict__ fmT, int H, int W,
          const float* __restrict__ fkey_w, const float* __restrict__ fkey_scale,
          const float* __restrict__ fkey_shift,
          const float* __restrict__ fval_w, const float* __restrict__ fval_b,
          unsigned short* __restrict__ keyT, unsigned short* __restrict__ valB) {
  __shared__ float pix[64][68];
  __shared__ __align__(16) unsigned short kout[64][80];
  __shared__ __align__(16) unsigned short vout[64][80];
  int tid = threadIdx.x;
  int b = blockIdx.x >> 2;
  int k0 = (blockIdx.x & 3) * 64;

  {
    int key = tid >> 2, cq = tid & 3;
    int k = k0 + key;
    float v[16];
    if (k < 250) {
      int r = k / 25, c2 = k % 25;
      int iy = (r * H) / 10, ix = (c2 * W) / 25;
      const unsigned short* src = fmT + ((size_t)b * H * W + iy * W + ix) * 64 + cq * 16;
      us8 a = *(const us8*)src;
      us8 bb = *(const us8*)(src + 8);
#pragma unroll
      for (int e = 0; e < 8; ++e) { v[e] = bf2f(a[e]); v[8 + e] = bf2f(bb[e]); }
    } else {
#pragma unroll
      for (int e = 0; e < 16; ++e) v[e] = 0.f;
    }
#pragma unroll
    for (int e = 0; e < 16; ++e) pix[key][cq * 16 + e] = v[e];
  }
  __syncthreads();

  {
    int o = tid >> 2, kq = tid & 3;
    float ak[16], av[16];
#pragma unroll
    for (int kk = 0; kk < 16; ++kk) { ak[kk] = 0.f; av[kk] = 0.f; }
    for (int c = 0; c < 64; ++c) {
      float wk = fkey_w[o * 64 + c], wvv = fval_w[o * 64 + c];
#pragma unroll
      for (int kk = 0; kk < 16; ++kk) {
        float pv = pix[kq * 16 + kk][c];
        ak[kk] += pv * wk; av[kk] += pv * wvv;
      }
    }
    float sc_ = fkey_scale[o], sh = fkey_shift[o], vb_ = fval_b[o];
#pragma unroll
    for (int kk = 0; kk < 16; ++kk) {
      int k = kq * 16 + kk;
      float kf = ak[kk] * sc_ + sh; kf = kf > 0.f ? kf : 0.f;
      kout[k][o] = f2bf(kf);
      vout[o][k] = f2bf(av[kk] + vb_);
    }
  }
  __syncthreads();

  {
    int row = tid >> 2, oq = tid & 3;
    *(us8*)(keyT + ((size_t)b * 256 + k0 + row) * 64 + oq * 16)     = *(us8*)&kout[row][oq * 16];
    *(us8*)(keyT + ((size_t)b * 256 + k0 + row) * 64 + oq * 16 + 8) = *(us8*)&kout[row][oq * 16 + 8];
    *(us8*)(valB + ((size_t)b * 64 + row) * 256 + k0 + oq * 16)     = *(us8*)&vout[row][oq * 16];
    *(us8*)(valB + ((size_t)b * 64 + row) * 256 + k0 + oq * 16 + 8) = *(us8*)&vout[row][oq * 16 + 8];
  }
}

// ---------------------------------------------------------------------------
// K1a: fused gather + conv_s (MFMA 16x16x32). k-loop fully unrolled;
// 3 blocks/CU requested.
// ---------------------------------------------------------------------------
template <int STAGE>
__global__ __launch_bounds__(256, 3)
void k_gatherconv(const unsigned short* __restrict__ fmT,
                  const float* __restrict__ priors_cur,
                  const unsigned short* __restrict__ Wr,
                  const float* __restrict__ cscale, const float* __restrict__ cshift,
                  unsigned short* __restrict__ cfg) {
  constexpr int H = (STAGE == 0) ? 64 : (STAGE == 1) ? 32 : 16;
  constexpr int W = (STAGE == 0) ? 80 : (STAGE == 1) ? 40 : 20;
  constexpr int HW = H * W;

  __shared__ float posx[8][36], posy[8][36];
  __shared__ __align__(16) unsigned short Xs[360][64];

  int tid = threadIdx.x;
  int r0 = blockIdx.x * 8;

  for (int idx = tid; idx < 288; idx += 256) {
    int q = idx / 36, j = idx % 36;
    int bp = r0 + q;
    int k = 35 - j;
    int sx = (int)(((float)k / 35.0f) * 71.0f);
    float px = priors_cur[(size_t)bp * 78 + 6 + sx];
    posx[q][j] = px * (float)(W - 1);
    float fy = 1.0f - (float)sx / 71.0f;
    posy[q][j] = fy * (float)(H - 1);
  }
  __syncthreads();

  for (int idx = tid; idx < 360 * 8; idx += 256) {
    int row = idx >> 3, ch8 = idx & 7;
    int p = row - 4;
    unsigned short pk[8] = {0, 0, 0, 0, 0, 0, 0, 0};
    if (p >= 0 && p < 352) {
      int q = p / 44, x = p % 44;
      if (x >= 4 && x < 40) {
        int j = x - 4;
        int b = (r0 + q) / PP;
        float fx = posx[q][j];
        float fy = posy[q][j];
        float x0 = floorf(fx), y0 = floorf(fy);
        float wx = fx - x0, wy = fy - y0;
        float xs2[2] = {x0, x0 + 1.f};
        float ys2[2] = {y0, y0 + 1.f};
        float wxs[2] = {1.f - wx, wx};
        float wys[2] = {1.f - wy, wy};
        float accf[8] = {0.f, 0.f, 0.f, 0.f, 0.f, 0.f, 0.f, 0.f};
#pragma unroll
        for (int ty = 0; ty < 2; ++ty)
#pragma unroll
          for (int tx = 0; tx < 2; ++tx) {
            float xf = xs2[tx], yf = ys2[ty];
            bool v = (xf >= 0.f) && (xf <= (float)(W - 1)) &&
                     (yf >= 0.f) && (yf <= (float)(H - 1));
            int xi = (int)fminf(fmaxf(xf, 0.f), (float)(W - 1));
            int yi = (int)fminf(fmaxf(yf, 0.f), (float)(H - 1));
            float wgt = v ? (wxs[tx] * wys[ty]) : 0.f;
            const us8 vv = *(const us8*)(fmT + ((size_t)b * HW + yi * W + xi) * 64 + ch8 * 8);
#pragma unroll
            for (int e = 0; e < 8; ++e) accf[e] += wgt * bf2f(vv[e]);
          }
#pragma unroll
        for (int e = 0; e < 8; ++e) pk[e] = f2bf(accf[e]);
      }
    }
    int pc = ch8 ^ (row & 7);
    *(us8*)&Xs[row][pc * 8] = *(us8*)pk;
  }
  __syncthreads();

  int wv = tid >> 6, lane = tid & 63, l15 = lane & 15, quad = lane >> 4;
  f32x4 acc[3][6];
#pragma unroll
  for (int m = 0; m < 3; ++m)
#pragma unroll
    for (int s = 0; s < 6; ++s) acc[m][s] = (f32x4)0.f;

#pragma unroll
  for (int k = 0; k < 9; ++k) {
#pragma unroll
    for (int kk = 0; kk < 2; ++kk) {
      bf16x8 af[3];
#pragma unroll
      for (int m = 0; m < 3; ++m)
        af[m] = ld8(Wr + ((size_t)(k * 48 + m * 16 + l15)) * 64 + kk * 32 + quad * 8);
#pragma unroll
      for (int s = 0; s < 6; ++s) {
        int nt = wv + 4 * s;
        if (nt < 22) {
          int row = nt * 16 + l15 + k;
          int pc = (kk * 4 + quad) ^ (row & 7);
          bf16x8 bfr = ld8(&Xs[row][pc * 8]);
#pragma unroll
          for (int m = 0; m < 3; ++m)
            acc[m][s] = __builtin_amdgcn_mfma_f32_16x16x32_bf16(af[m], bfr, acc[m][s], 0, 0, 0);
        }
      }
    }
  }

#pragma unroll
  for (int s = 0; s < 6; ++s) {
    int nt = wv + 4 * s;
    if (nt < 22) {
      int p = nt * 16 + l15;
      int q = p / 44, x = p % 44;
      if (x >= 4 && x < 40) {
        int bp = r0 + q;
#pragma unroll
        for (int m = 0; m < 3; ++m) {
          int o0 = m * 16 + quad * 4;
          unsigned short pk[4];
#pragma unroll
          for (int rg = 0; rg < 4; ++rg) {
            float v = acc[m][s][rg] * cscale[o0 + rg] + cshift[o0 + rg];
            pk[rg] = f2bf(v > 0.f ? v : 0.f);
          }
          *(uint2*)(cfg + ((size_t)bp * 36 + (x - 4)) * 48 + o0) = *(uint2*)pk;
        }
      }
    }
  }
}

// ---------------------------------------------------------------------------
// K1b: cat conv with 32x32x16 MFMA. t-loop fully unrolled so the compiler
// can hoist A loads (imm-offset buffer loads) far ahead of the MFMAs;
// 3 blocks/CU requested.
// ---------------------------------------------------------------------------
template <int STAGE>
__global__ __launch_bounds__(256, 3)
void k_cat(const unsigned short* __restrict__ cfg_all,
           const unsigned short* __restrict__ Wc,
           const float* __restrict__ kscale, const float* __restrict__ kshift,
           unsigned short* __restrict__ catf) {
  constexpr int NC = STAGE + 1;
  __shared__ __align__(16) unsigned short cfs[360][64];
  int tid = threadIdx.x;
  int r0 = blockIdx.x * 8;
  int wv = tid >> 6, lane = tid & 63;
  int l31 = lane & 31, half = lane >> 5;

  int nt0 = wv * 3;
  int ntn = (wv < 3) ? 3 : 2;       // 11 n-tiles total

  f32x16 acc[2][3];
#pragma unroll
  for (int m = 0; m < 2; ++m)
#pragma unroll
    for (int n = 0; n < 3; ++n) acc[m][n] = (f32x16)0.f;

#pragma unroll
  for (int i = 0; i < NC; ++i) {
    __syncthreads();
    for (int idx = tid; idx < 2160; idx += 256) {
      int row = idx / 6, ch = idx % 6;
      int p = row - 4;
      us8 v = (us8)(unsigned short)0;
      if (p >= 0 && p < 352) {
        int q = p / 44, x = p % 44;
        if (x >= 4 && x < 40) {
          v = *(const us8*)(cfg_all + (size_t)i * (12288ull * 36 * 48) +
                            ((size_t)(r0 + q) * 36 + (x - 4)) * 48 + ch * 8);
        }
      }
      *(us8*)&cfs[row][((ch ^ (row & 7)) * 8)] = v;
    }
    __syncthreads();

#pragma unroll
    for (int t = 0; t < 9; ++t) {
#pragma unroll
      for (int s = 0; s < 3; ++s) {
        int slice_id = i * 27 + t * 3 + s;
        bf16x8 a0 = ld8(Wc + (size_t)(slice_id * 2 + 0) * 512 + lane * 8);
        bf16x8 a1 = ld8(Wc + (size_t)(slice_id * 2 + 1) * 512 + lane * 8);
#pragma unroll
        for (int n = 0; n < 3; ++n) {
          if (n < ntn) {
            int row = (nt0 + n) * 32 + l31 + t;
            int q = (s * 2 + half) ^ (row & 7);
            bf16x8 b = ld8(&cfs[row][q * 8]);
            acc[0][n] = __builtin_amdgcn_mfma_f32_32x32x16_bf16(a0, b, acc[0][n], 0, 0, 0);
            acc[1][n] = __builtin_amdgcn_mfma_f32_32x32x16_bf16(a1, b, acc[1][n], 0, 0, 0);
          }
        }
      }
    }
  }

#pragma unroll
  for (int n = 0; n < 3; ++n) {
    if (n < ntn) {
      int p = (nt0 + n) * 32 + l31;
      int q = p / 44, x = p % 44;
      if (x >= 4 && x < 40) {
        int bp = r0 + q;
        unsigned short* dst = catf + ((size_t)bp * 36 + (x - 4)) * 64;
#pragma unroll
        for (int m = 0; m < 2; ++m) {
#pragma unroll
          for (int r = 0; r < 4; ++r) {
            int o0 = m * 32 + r * 8 + half * 4;
            unsigned short pk[4];
#pragma unroll
            for (int g = 0; g < 4; ++g) {
              int o = o0 + g;
              float v = acc[m][n][r * 4 + g] * kscale[o] + kshift[o];
              pk[g] = f2bf(v > 0.f ? v : 0.f);
            }
            *(uint2*)(dst + o0) = *(uint2*)pk;
          }
        }
      }
    }
  }
}

// ---------------------------------------------------------------------------
// K1c: fc GEMM + bias + LayerNorm + relu. One wave per 16 rois; grid = 768
// (was 192x256 = only 0.75 blocks/CU — a quarter of the GPU idle).
// ---------------------------------------------------------------------------
__global__ __launch_bounds__(64)
void k_fc(const unsigned short* __restrict__ catf,
          const unsigned short* __restrict__ fw,
          const float* __restrict__ fc_b,
          const float* __restrict__ ln_g, const float* __restrict__ ln_b,
          float* __restrict__ roi_fc) {
  __shared__ __align__(16) float fcb[16][68];
  int lane = threadIdx.x, l15 = lane & 15, quad = lane >> 4;
  int nbase = blockIdx.x * 16;

  f32x4 acc[4];
#pragma unroll
  for (int m = 0; m < 4; ++m) acc[m] = (f32x4)0.f;

  for (int ks = 0; ks < 72; ++ks) {
    int j = ks >> 1, ch = (ks & 1) * 32;
    bf16x8 bfr = ld8(catf + ((size_t)(nbase + l15) * 36 + j) * 64 + ch + quad * 8);
#pragma unroll
    for (int m = 0; m < 4; ++m) {
      bf16x8 af = ld8(fw + (size_t)(m * 16 + l15) * 2304 + ks * 32 + quad * 8);
      acc[m] = __builtin_amdgcn_mfma_f32_16x16x32_bf16(af, bfr, acc[m], 0, 0, 0);
    }
  }

#pragma unroll
  for (int m = 0; m < 4; ++m) {
    f32x4 v;
#pragma unroll
    for (int rg = 0; rg < 4; ++rg) v[rg] = acc[m][rg] + fc_b[m * 16 + quad * 4 + rg];
    *(f32x4*)&fcb[l15][m * 16 + quad * 4] = v;
  }
  __syncthreads();

  for (int rr = 0; rr < 16; ++rr) {
    float y = fcb[rr][lane];
    float s = y;
#pragma unroll
    for (int off = 32; off > 0; off >>= 1) s += __shfl_xor(s, off, 64);
    float mu = s * (1.f / 64.f);
    float d = y - mu;
    float v2 = d * d;
#pragma unroll
    for (int off = 32; off > 0; off >>= 1) v2 += __shfl_xor(v2, off, 64);
    float var = v2 * (1.f / 64.f);
    float r = d / sqrtf(var + 1e-5f) * ln_g[lane] + ln_b[lane];
    roi_fc[(size_t)(nbase + rr) * 64 + lane] = r > 0.f ? r : 0.f;
  }
}

// ---------------------------------------------------------------------------
// helper: one 16(M)x16(N)x64(K) GEMM tile.
// ---------------------------------------------------------------------------
__device__ inline f32x4 gemm_tile(const unsigned short* __restrict__ Wrow0,
                                  const unsigned short* Xl, int l15, int quad) {
  f32x4 a = (f32x4)0.f;
#pragma unroll
  for (int kk = 0; kk < 2; ++kk) {
    bf16x8 af = ld8(Wrow0 + (size_t)l15 * 64 + kk * 32 + quad * 8);
    bf16x8 bx = ld8(Xl + l15 * 64 + (((kk * 4 + quad) ^ (l15 & 7)) * 8));
    a = __builtin_amdgcn_mfma_f32_16x16x32_bf16(af, bx, a, 0, 0, 0);
  }
  return a;
}

// ---------------------------------------------------------------------------
// K3: batched attention + MLP heads + tan epilogue, all MFMA.
// One wave per 16 rois; grid = 768 (was 192 blocks = 0.75/CU).
// ---------------------------------------------------------------------------
__global__ __launch_bounds__(64)
void k_att2(const float* __restrict__ roi_fc,
            const unsigned short* __restrict__ keyT,
            const unsigned short* __restrict__ valB,
            const float* __restrict__ fq_w, const float* __restrict__ fq_b,
            const float* __restrict__ attW_w, const float* __restrict__ attW_b,
            const unsigned short* __restrict__ wm,
            const float* __restrict__ cls_mlp_b, const float* __restrict__ reg_mlp_b,
            const float* __restrict__ cls_head_b, const float* __restrict__ reg_head_b,
            const float* __restrict__ priors_cur,
            float* __restrict__ priors_next,
            float* __restrict__ preds) {
  __shared__ __align__(16) unsigned char smem[2048 + 4608 + 8192];
  unsigned short* qx = (unsigned short*)smem;            // q / x union [16][64]
  unsigned char* Bb = smem + 2048;                       // rf / hA,hB union
  unsigned char* Cb = smem + 2048 + 4608;                // sim / rego union

  int lane = threadIdx.x;
  int l15 = lane & 15, quad = lane >> 4;
  int rb = blockIdx.x * 16;
  int b = rb / PP;
  int p_base = rb % PP;

  float* rf = (float*)Bb;                                // [16][68] f32
  unsigned short* hA = (unsigned short*)Bb;              // [16][64] bf16
  unsigned short* hB = (unsigned short*)(Bb + 2304);
  unsigned short* simw = (unsigned short*)Cb;            // [16][256] bf16
  unsigned short* rego = (unsigned short*)Cb;            // [16][80] bf16
  unsigned short* clso = (unsigned short*)(Cb + 2560);   // [16][2]

  // ---- phase 1: load roi_fc -> rf (f32) + q (bf16, swizzled) ----
  for (int it = lane; it < 128; it += 64) {
    int row = it >> 3, ch = it & 7;
    const float* src = roi_fc + (size_t)(rb + row) * 64 + ch * 8;
    float v[8];
#pragma unroll
    for (int e = 0; e < 8; ++e) v[e] = src[e];
#pragma unroll
    for (int e = 0; e < 8; ++e) rf[row * 68 + ch * 8 + e] = v[e];
    int p = p_base + row;
    float qw = fq_w[p], qb = fq_b[p];
    unsigned short pk[8];
#pragma unroll
    for (int e = 0; e < 8; ++e) {
      float q = v[e] * qw + qb;
      pk[e] = f2bf(q > 0.f ? q : 0.f);
    }
    *(us8*)&qx[row * 64 + ((ch ^ (row & 7)) * 8)] = *(us8*)pk;
  }
  __syncthreads();

  // ---- phase 2: QK^T + in-register softmax ----
  f32x4 sc[16];
#pragma unroll
  for (int nt = 0; nt < 16; ++nt) sc[nt] = (f32x4)0.f;
  const unsigned short* kb = keyT + (size_t)b * 256 * 64;
#pragma unroll
  for (int kk = 0; kk < 2; ++kk) {
    bf16x8 af = ld8(&qx[l15 * 64 + (((kk * 4 + quad) ^ (l15 & 7)) * 8)]);
#pragma unroll
    for (int nt = 0; nt < 16; ++nt) {
      bf16x8 bf_ = ld8(kb + (size_t)(nt * 16 + l15) * 64 + kk * 32 + quad * 8);
      sc[nt] = __builtin_amdgcn_mfma_f32_16x16x32_bf16(af, bf_, sc[nt], 0, 0, 0);
    }
  }
  float mx[4] = {-1e30f, -1e30f, -1e30f, -1e30f};
#pragma unroll
  for (int nt = 0; nt < 16; ++nt)
#pragma unroll
    for (int rg = 0; rg < 4; ++rg) {
      float s = sc[nt][rg] * 0.125f;
      if (nt == 15 && l15 >= 10) s = -1e30f;
      sc[nt][rg] = s;
      mx[rg] = fmaxf(mx[rg], s);
    }
#pragma unroll
  for (int rg = 0; rg < 4; ++rg)
#pragma unroll
    for (int off = 1; off < 16; off <<= 1)
      mx[rg] = fmaxf(mx[rg], __shfl_xor(mx[rg], off, 64));
  float sm[4] = {0.f, 0.f, 0.f, 0.f};
#pragma unroll
  for (int nt = 0; nt < 16; ++nt)
#pragma unroll
    for (int rg = 0; rg < 4; ++rg) {
      float e = expf(sc[nt][rg] - mx[rg]);
      sc[nt][rg] = e;
      sm[rg] += e;
    }
#pragma unroll
  for (int rg = 0; rg < 4; ++rg)
#pragma unroll
    for (int off = 1; off < 16; off <<= 1)
      sm[rg] += __shfl_xor(sm[rg], off, 64);
  float rs[4];
#pragma unroll
  for (int rg = 0; rg < 4; ++rg) rs[rg] = 1.f / sm[rg];
#pragma unroll
  for (int nt = 0; nt < 16; ++nt)
#pragma unroll
    for (int rg = 0; rg < 4; ++rg) {
      int row = quad * 4 + rg, col = nt * 16 + l15;
      simw[row * 256 + (((col >> 3) ^ (row & 7)) * 8) + (col & 7)] = f2bf(sc[nt][rg] * rs[rg]);
    }

  // ---- phase 3: PV + residual + attW ----
  f32x4 cv[4];
#pragma unroll
  for (int nt = 0; nt < 4; ++nt) cv[nt] = (f32x4)0.f;
  const unsigned short* vb = valB + (size_t)b * 64 * 256;
#pragma unroll
  for (int ks = 0; ks < 8; ++ks) {
    bf16x8 af = ld8(&simw[l15 * 256 + (((ks * 4 + quad) ^ (l15 & 7)) * 8)]);
#pragma unroll
    for (int nt = 0; nt < 4; ++nt) {
      bf16x8 bf_ = ld8(vb + (size_t)(nt * 16 + l15) * 256 + ks * 32 + quad * 8);
      cv[nt] = __builtin_amdgcn_mfma_f32_16x16x32_bf16(af, bf_, cv[nt], 0, 0, 0);
    }
  }
#pragma unroll
  for (int rg = 0; rg < 4; ++rg) {
    int row = quad * 4 + rg;
    int p = p_base + row;
    float aw = attW_w[p], ab = attW_b[p];
#pragma unroll
    for (int nt = 0; nt < 4; ++nt) {
      int c = nt * 16 + l15;
      float xv = rf[row * 68 + c] + cv[nt][rg] * aw + ab;
      qx[row * 64 + (((c >> 3) ^ (row & 7)) * 8) + (c & 7)] = f2bf(xv);
    }
  }

  // ---- phase 4: MLP chains ----
  const unsigned short* xw = qx;
#pragma unroll
  for (int mt = 0; mt < 4; ++mt) {
    f32x4 a = gemm_tile(wm + 0 + mt * 1024, xw, l15, quad);
#pragma unroll
    for (int rg = 0; rg < 4; ++rg) {
      int o = mt * 16 + quad * 4 + rg;
      float v = a[rg] + cls_mlp_b[o]; v = v > 0.f ? v : 0.f;
      hA[l15 * 64 + (((o >> 3) ^ (l15 & 7)) * 8) + (o & 7)] = f2bf(v);
    }
  }
#pragma unroll
  for (int mt = 0; mt < 4; ++mt) {
    f32x4 a = gemm_tile(wm + 4096 + mt * 1024, hA, l15, quad);
#pragma unroll
    for (int rg = 0; rg < 4; ++rg) {
      int o = mt * 16 + quad * 4 + rg;
      float v = a[rg] + cls_mlp_b[64 + o]; v = v > 0.f ? v : 0.f;
      hB[l15 * 64 + (((o >> 3) ^ (l15 & 7)) * 8) + (o & 7)] = f2bf(v);
    }
  }
  {
    f32x4 a = gemm_tile(wm + 16384, hB, l15, quad);
#pragma unroll
    for (int rg = 0; rg < 4; ++rg) {
      int o = quad * 4 + rg;
      if (o < 2) clso[l15 * 2 + o] = f2bf(a[rg] + cls_head_b[o]);
    }
  }
#pragma unroll
  for (int mt = 0; mt < 4; ++mt) {
    f32x4 a = gemm_tile(wm + 8192 + mt * 1024, xw, l15, quad);
#pragma unroll
    for (int rg = 0; rg < 4; ++rg) {
      int o = mt * 16 + quad * 4 + rg;
      float v = a[rg] + reg_mlp_b[o]; v = v > 0.f ? v : 0.f;
      hA[l15 * 64 + (((o >> 3) ^ (l15 & 7)) * 8) + (o & 7)] = f2bf(v);
    }
  }
#pragma unroll
  for (int mt = 0; mt < 4; ++mt) {
    f32x4 a = gemm_tile(wm + 12288 + mt * 1024, hA, l15, quad);
#pragma unroll
    for (int rg = 0; rg < 4; ++rg) {
      int o = mt * 16 + quad * 4 + rg;
      float v = a[rg] + reg_mlp_b[64 + o]; v = v > 0.f ? v : 0.f;
      hB[l15 * 64 + (((o >> 3) ^ (l15 & 7)) * 8) + (o & 7)] = f2bf(v);
    }
  }
#pragma unroll
  for (int mt = 0; mt < 5; ++mt) {
    f32x4 a = gemm_tile(wm + 17408 + mt * 1024, hB, l15, quad);
#pragma unroll
    for (int rg = 0; rg < 4; ++rg) {
      int o = mt * 16 + quad * 4 + rg;
      if (o < 76) rego[l15 * 80 + o] = f2bf(a[rg] + reg_head_b[o]);
    }
  }

  // ---- phase 5: epilogue (4 lanes per roi) ----
  {
    int p_local = lane >> 2, g = lane & 3;
    int bp = rb + p_local;
    const float* pc = priors_cur + (size_t)bp * 78;
    float r0v = bf2f(rego[p_local * 80 + 0]);
    float r1v = bf2f(rego[p_local * 80 + 1]);
    float r2v = bf2f(rego[p_local * 80 + 2]);
    float r3v = bf2f(rego[p_local * 80 + 3]);
    float p0 = pc[2] + r0v;
    float p1 = pc[3] + r1v;
    float p2 = pc[4] + r2v;
    float* po = preds + (size_t)bp * 78;
    float* pn = priors_next ? priors_next + (size_t)bp * 78 : nullptr;
    if (g == 0) {
      float c0v = bf2f(clso[p_local * 2 + 0]);
      float c1v = bf2f(clso[p_local * 2 + 1]);
      po[0] = c0v; po[1] = c1v;
      po[2] = p0; po[3] = p1; po[4] = p2; po[5] = r3v;
      if (pn) { pn[0] = c0v; pn[1] = c1v; pn[2] = p0; pn[3] = p1; pn[4] = p2; pn[5] = r3v; }
    }
    float t = tanf(p2 * PI_F + 1e-5f);
    float inv_t = 512.f / t;
#pragma unroll 2
    for (int i = g * 18; i < g * 18 + 18; ++i) {
      float py = 1.0f - (float)i / 71.0f;
      float offs = (p1 * 639.0f + (1.0f - py - p0) * inv_t) * (1.0f / 639.0f);
      po[6 + i] = offs + bf2f(rego[p_local * 80 + 4 + i]);
      if (pn) pn[6 + i] = offs;
    }
  }
}

// ---------------------------------------------------------------------------
extern "C" void kernel_launch(void* const* d_in, const int* in_sizes, int n_in,
                              void* d_out, int out_size, void* d_ws, size_t ws_size,
                              hipStream_t stream) {
  (void)in_sizes; (void)n_in; (void)out_size; (void)ws_size;
  const float* feat[3] = {(const float*)d_in[0], (const float*)d_in[1], (const float*)d_in[2]};
  const float* priors      = (const float*)d_in[3];
  const float* convs_w     = (const float*)d_in[4];
  const float* convs_scale = (const float*)d_in[5];
  const float* convs_shift = (const float*)d_in[6];
  const float* cat_w[3]    = {(const float*)d_in[7], (const float*)d_in[8], (const float*)d_in[9]};
  const float* cat_scale   = (const float*)d_in[10];
  const float* cat_shift   = (const float*)d_in[11];
  const float* fkey_w      = (const float*)d_in[12];
  const float* fkey_scale  = (const float*)d_in[13];
  const float* fkey_shift  = (const float*)d_in[14];
  const float* fval_w      = (const float*)d_in[15];
  const float* fval_b      = (const float*)d_in[16];
  const float* fq_w        = (const float*)d_in[17];
  const float* fq_b        = (const float*)d_in[18];
  const float* attW_w      = (const float*)d_in[19];
  const float* attW_b      = (const float*)d_in[20];
  const float* fc_w        = (const float*)d_in[21];
  const float* fc_b        = (const float*)d_in[22];
  const float* ln_g        = (const float*)d_in[23];
  const float* ln_b        = (const float*)d_in[24];
  const float* cls_mlp_w   = (const float*)d_in[25];
  const float* cls_mlp_b   = (const float*)d_in[26];
  const float* reg_mlp_w   = (const float*)d_in[27];
  const float* reg_mlp_b   = (const float*)d_in[28];
  const float* cls_head_w  = (const float*)d_in[29];
  const float* cls_head_b  = (const float*)d_in[30];
  const float* reg_head_w  = (const float*)d_in[31];
  const float* reg_head_b  = (const float*)d_in[32];
  float* out = (float*)d_out;

  char* wp = (char*)d_ws;
  auto alloc = [&](size_t bytes) { char* r = wp; wp += (bytes + 255) & ~(size_t)255; return r; };

  float* priA   = (float*)alloc((size_t)BB * PP * 78 * 4);
  float* priB   = (float*)alloc((size_t)BB * PP * 78 * 4);
  float* roi_fc = (float*)alloc((size_t)BB * PP * 64 * 4);
  unsigned short* keyT = (unsigned short*)alloc((size_t)BB * 256 * 64 * 2);
  unsigned short* valB = (unsigned short*)alloc((size_t)BB * 64 * 256 * 2);
  unsigned short* Wr   = (unsigned short*)alloc(82944ull * 2);
  unsigned short* Wc   = (unsigned short*)alloc(165888ull * 2);
  unsigned short* fw   = (unsigned short*)alloc(147456ull * 2);
  unsigned short* wm   = (unsigned short*)alloc(22528ull * 2);
  unsigned short* cfg  = (unsigned short*)alloc(3ull * 12288 * 36 * 48 * 2);
  unsigned short* catf = (unsigned short*)alloc(12288ull * 36 * 64 * 2);
  unsigned short* fmT  = (unsigned short*)alloc((size_t)BB * 64 * 80 * 64 * 2);

  const int HW[3][2] = {{64, 80}, {32, 40}, {16, 20}};
  const size_t wcoff[3] = {0, 27648, 82944};

  k_init_priors<<<dim3((BB * PP * 78 + 255) / 256), dim3(256), 0, stream>>>(priors, priA);
  k_repack<<<dim3((418816 + 255) / 256), dim3(256), 0, stream>>>(
      convs_w, cat_w[0], cat_w[1], cat_w[2], fc_w,
      cls_mlp_w, reg_mlp_w, cls_head_w, reg_head_w, Wr, Wc, fw, wm);

  float* pcur = priA;
  float* pnext = priB;
  for (int s = 0; s < 3; ++s) {
    int H = HW[s][0], W = HW[s][1];
    int hw = H * W;
    int tiles = hw / 64;
    k_transpose<<<dim3(BB * tiles), dim3(256), 0, stream>>>(feat[s], hw, tiles, fmT);

    k_kv<<<dim3(BB * 4), dim3(256), 0, stream>>>(
        fmT, H, W, fkey_w, fkey_scale, fkey_shift, fval_w, fval_b, keyT, valB);

    if (s == 0) {
      k_gatherconv<0><<<dim3(1536), dim3(256), 0, stream>>>(
          fmT, pcur, Wr + 0 * 27648, convs_scale + 0, convs_shift + 0,
          cfg + 0ull * 12288 * 36 * 48);
      k_cat<0><<<dim3(1536), dim3(256), 0, stream>>>(
          cfg, Wc + wcoff[0], cat_scale + 0, cat_shift + 0, catf);
    } else if (s == 1) {
      k_gatherconv<1><<<dim3(1536), dim3(256), 0, stream>>>(
          fmT, pcur, Wr + 1 * 27648, convs_scale + 48, convs_shift + 48,
          cfg + 1ull * 12288 * 36 * 48);
      k_cat<1><<<dim3(1536), dim3(256), 0, stream>>>(
          cfg, Wc + wcoff[1], cat_scale + 64, cat_shift + 64, catf);
    } else {
      k_gatherconv<2><<<dim3(1536), dim3(256), 0, stream>>>(
          fmT, pcur, Wr + 2 * 27648, convs_scale + 96, convs_shift + 96,
          cfg + 2ull * 12288 * 36 * 48);
      k_cat<2><<<dim3(1536), dim3(256), 0, stream>>>(
          cfg, Wc + wcoff[2], cat_scale + 128, cat_shift + 128, catf);
    }

    k_fc<<<dim3(768), dim3(64), 0, stream>>>(catf, fw, fc_b, ln_g, ln_b, roi_fc);

    k_att2<<<dim3(768), dim3(64), 0, stream>>>(
        roi_fc, keyT, valB, fq_w, fq_b, attW_w, attW_b, wm,
        cls_mlp_b, reg_mlp_b, cls_head_b, reg_head_b,
        pcur, (s < 2) ? pnext : (float*)nullptr,
        out + (size_t)s * BB * PP * 78);

    float* tmp = pcur; pcur = pnext; pnext = tmp;
  }
}